// Round 3
// baseline (16361.264 us; speedup 1.0000x reference)
//
#include <hip/hip_runtime.h>
#include <hip/hip_fp16.h>

#define BS 256
#define T 256
#define STEPS 255
#define WV 100
#define INP 64
#define H 256
#define G4 1024
#define VOCAB 600

// ---------------- packed f16 dot2 with f32 accumulate ---------------------
typedef _Float16 f16x2 __attribute__((ext_vector_type(2)));

__device__ __forceinline__ float fdot2(unsigned w, unsigned h, float acc) {
#if defined(__has_builtin) && __has_builtin(__builtin_amdgcn_fdot2)
    return __builtin_amdgcn_fdot2(__builtin_bit_cast(f16x2, w),
                                  __builtin_bit_cast(f16x2, h), acc, false);
#else
    __half2 wv = *(const __half2*)&w;
    __half2 hv = *(const __half2*)&h;
    float2 wf = __half22float2(wv), hf = __half22float2(hv);
    return acc + wf.x * hf.x + wf.y * hf.y;
#endif
}

// ---------------- sort: stable descending by length (jax argsort(-len)) ----
__global__ void k_sort(const int* __restrict__ lens, int* __restrict__ sidx,
                       int* __restrict__ dlen, float* __restrict__ out_dec,
                       float* __restrict__ out_sidx) {
    __shared__ int L[BS];
    int i = threadIdx.x;
    L[i] = lens[i];
    __syncthreads();
    int li = L[i];
    int r = 0;
    for (int j = 0; j < BS; ++j) {
        int lj = L[j];
        r += (lj > li) || (lj == li && j < i);
    }
    sidx[r] = i;
    dlen[r] = li - 1;
    out_sidx[r] = (float)i;
    out_dec[r]  = (float)(li - 1);
}

// ---------------- gather sorted captions to output ------------------------
__global__ void k_gather(const float* __restrict__ cin, const int* __restrict__ sidx,
                         float* __restrict__ cout) {
    int b = blockIdx.x;
    int src = sidx[b];
    const float4* in  = (const float4*)(cin + (size_t)src * T * WV);
    float4* out       = (float4*)(cout + (size_t)b * T * WV);
    for (int i = threadIdx.x; i < T * WV / 4; i += 256) out[i] = in[i];
}

// ---------------- W_comb = w_ih @ W_emb^T  [1024 x 100] -------------------
__global__ void k_wcomb(const float* __restrict__ w_ih, const float* __restrict__ W_emb,
                        float* __restrict__ Wc) {
    int idx = blockIdx.x * 256 + threadIdx.x;   // 102400 threads
    int r = idx / WV, cc = idx % WV;
    float acc = 0.f;
    for (int k = 0; k < INP; ++k) acc += w_ih[r * INP + k] * W_emb[k * WV + cc];
    Wc[idx] = acc;
}

// ---------------- b_comb = b_ih + b_hh + w_ih @ b_emb ---------------------
__global__ void k_bcomb(const float* __restrict__ w_ih, const float* __restrict__ b_ih,
                        const float* __restrict__ b_hh, const float* __restrict__ b_emb,
                        float* __restrict__ bc) {
    int r = blockIdx.x * 256 + threadIdx.x;     // 1024 threads
    float acc = b_ih[r] + b_hh[r];
    for (int k = 0; k < INP; ++k) acc += w_ih[r * INP + k] * b_emb[k];
    bc[r] = acc;
}

// ---------------- pack w_hh -> fp16, k-major transposed -------------------
// wT[k2*1024 + r] = half2(w_hh[r][2k2], w_hh[r][2k2+1])
__global__ void k_packw(const float* __restrict__ w_hh, __half2* __restrict__ wT) {
    int idx = blockIdx.x * 256 + threadIdx.x;   // 131072 threads
    int k2 = idx >> 10, r = idx & 1023;
    wT[(size_t)k2 * G4 + r] =
        __floats2half2_rn(w_hh[(size_t)r * H + 2 * k2], w_hh[(size_t)r * H + 2 * k2 + 1]);
}

// ---------------- h0 = enc@W_h^T + b_h ; c0 = enc@W_c^T + b_c -------------
__global__ void k_inithc(const float* __restrict__ enc, const int* __restrict__ sidx,
                         const float* __restrict__ W_h, const float* __restrict__ b_h,
                         const float* __restrict__ W_c, const float* __restrict__ b_c,
                         float* __restrict__ h_st, float* __restrict__ c_st) {
    int b = blockIdx.x, j = threadIdx.x;
    __shared__ __align__(16) float e[INP];
    int src = sidx[b];
    if (j < INP) e[j] = enc[src * INP + j];
    __syncthreads();
    const float4* e4  = (const float4*)e;
    const float4* wh4 = (const float4*)(W_h + (size_t)j * INP);
    const float4* wc4 = (const float4*)(W_c + (size_t)j * INP);
    float ah = b_h[j], ac = b_c[j];
    #pragma unroll
    for (int k4 = 0; k4 < INP / 4; ++k4) {
        float4 ev = e4[k4];
        float4 wh = wh4[k4];
        float4 wc = wc4[k4];
        ah += ev.x * wh.x + ev.y * wh.y + ev.z * wh.z + ev.w * wh.w;
        ac += ev.x * wc.x + ev.y * wc.y + ev.z * wc.z + ev.w * wc.w;
    }
    h_st[b * H + j] = ah;
    c_st[b * H + j] = ac;
}

// ---------------- xg[b,ct,:] = caps_sorted[b,t,:] @ W_comb^T + b_comb -----
// 32-timestep tiles, 4 sequential column passes (acc[32] each).
__global__ void k_xg(const float* __restrict__ caps, const float* __restrict__ Wc,
                     const float* __restrict__ bc, const int* __restrict__ dlen,
                     float* __restrict__ xg, int t0, int Cc) {
    int b = blockIdx.y;
    int ct0 = blockIdx.x * 32;
    if (t0 + ct0 >= dlen[b]) return;   // rows never consumed by the LSTM
    __shared__ __align__(16) float4 cs4[32][WV / 4];   // 32 timesteps x 100
    float* cs = (float*)cs4;
    for (int i = threadIdx.x; i < 32 * WV; i += 256) {
        int rr = i / WV, k = i % WV;
        int t = t0 + ct0 + rr;
        cs[rr * WV + k] = (t < T && ct0 + rr < Cc) ? caps[((size_t)b * T + t) * WV + k] : 0.f;
    }
    __syncthreads();
    int nrow = Cc - ct0; if (nrow > 32) nrow = 32;
    for (int rq = 0; rq < 4; ++rq) {
        int r = threadIdx.x + rq * 256;
        float acc[32];
        float bv = bc[r];
        #pragma unroll
        for (int rr = 0; rr < 32; ++rr) acc[rr] = bv;
        const float4* wr = (const float4*)(Wc + (size_t)r * WV);
        for (int k4 = 0; k4 < WV / 4; ++k4) {
            float4 w = wr[k4];
            #pragma unroll
            for (int rr = 0; rr < 32; ++rr) {
                float4 av = cs4[rr][k4];
                acc[rr] += av.x * w.x + av.y * w.y + av.z * w.z + av.w * w.w;
            }
        }
        for (int rr = 0; rr < nrow; ++rr)
            xg[((size_t)b * Cc + ct0 + rr) * G4 + r] = acc[rr];
    }
}

// ---------------- recurrent LSTM core: one block per batch row ------------
// 512 threads, ALL w_hh weights on-chip:
//   rows 0..511 (i,f): thread t holds row t in regs      (128 half2 dwords)
//   rows 512..767 (g): pair (j, j+256) split K-halves    ( 64 half2 dwords)
//   rows 768..1023(o): LDS, uint4-packed [c8][256]       (128 KB, b128 reads)
// h broadcast from LDS as hi/lo f16 split (error ~= f32-h path).
// Merged loop: g/o dots reuse the own-row h-chunks -> 80 LDS insts/step
// (was 160: 96 b128 + 64 b32). Identical dot pairing => bitwise-same sums.
#define LSTM_SMEM (131072 + 3 * 512 * 4 + 2 * 256 * 2)   // 138240 B

__global__ __launch_bounds__(512, 1) void k_lstm(const __half2* __restrict__ wT,
        const float* __restrict__ xg, const int* __restrict__ dlen,
        float* __restrict__ h_st, float* __restrict__ c_st,
        __half* __restrict__ hck, int t0, int Cc) {
    extern __shared__ __align__(16) char smem[];
    uint4* o_lds4 = (uint4*)smem;                       // [32][256] uint4 (k2 quads)
    float* sA = (float*)(smem + 131072);                // 512: i/f sigmoids
    float* sG = sA + 512;                               // 512: g partials
    float* sO = sG + 512;                               // 512: o partials
    __half* hhi = (__half*)(sO + 512);                  // 256 (16B aligned)
    __half* hlo = hhi + 256;                            // 256

    int b = blockIdx.x, tid = threadIdx.x;
    int steps_b = dlen[b];
    if (t0 >= steps_b) return;

    const unsigned* wTu = (const unsigned*)wT;
    int r  = tid & 255;
    int kh = __builtin_amdgcn_readfirstlane(tid >> 8);  // wave-uniform K-half

    // ---- preload all recurrent weights on-chip (once per launch) ----
    unsigned wo[128];             // own row `tid` (i for tid<256, f else)
    #pragma unroll
    for (int k2 = 0; k2 < 128; ++k2) wo[k2] = wTu[k2 * G4 + tid];
    unsigned wg[64];              // g-row 512+r, K-half kh
    #pragma unroll
    for (int i = 0; i < 64; ++i) wg[i] = wTu[(kh * 64 + i) * G4 + 512 + r];
    for (int i = tid; i < 32 * 256; i += 512) {         // o rows -> LDS uint4-packed
        int c8 = i >> 8, rr = i & 255;
        uint4 v;
        v.x = wTu[(4 * c8 + 0) * G4 + 768 + rr];
        v.y = wTu[(4 * c8 + 1) * G4 + 768 + rr];
        v.z = wTu[(4 * c8 + 2) * G4 + 768 + rr];
        v.w = wTu[(4 * c8 + 3) * G4 + 768 + rr];
        o_lds4[i] = v;
    }

    float c = 0.f, hcur = 0.f;
    if (tid < H) {
        hcur = h_st[b * H + tid];
        c    = c_st[b * H + tid];
        __half hh16 = __float2half(hcur);
        hhi[tid] = hh16;
        hlo[tid] = __float2half(hcur - __half2float(hh16));
    }
    __syncthreads();

    const uint4* hhi4 = (const uint4*)hhi;   // 4 half2 per read (broadcast)
    const uint4* hlo4 = (const uint4*)hlo;
    int tend = t0 + Cc; if (tend > steps_b) tend = steps_b;
    const float* xgp = xg + (size_t)b * Cc * G4;
    __half* hckp = hck + (size_t)b * Cc * H;

    for (int t = t0; t < tend; ++t) {
        float xa = xgp[tid];                 // consumed after dot phase
        float xgg = 0.f, xgo = 0.f;
        if (tid < H) { xgg = xgp[512 + tid]; xgo = xgp[768 + tid]; }

        // ---- merged loop: own i/f full-K dots; g/o dots piggyback on the
        //      matching h-chunks (wave-uniform branch, no divergence) ----
        float ah0 = 0.f, ah1 = 0.f, ah2 = 0.f, ah3 = 0.f;
        float al0 = 0.f, al1 = 0.f, al2 = 0.f, al3 = 0.f;
        float gh0 = 0.f, gh1 = 0.f, gl0 = 0.f, gl1 = 0.f;
        float oh0 = 0.f, oh1 = 0.f, ol0 = 0.f, ol1 = 0.f;
        #pragma unroll
        for (int c8 = 0; c8 < 32; ++c8) {
            uint4 hh = hhi4[c8];
            uint4 hl = hlo4[c8];
            ah0 = fdot2(wo[4 * c8 + 0], hh.x, ah0);
            ah1 = fdot2(wo[4 * c8 + 1], hh.y, ah1);
            ah2 = fdot2(wo[4 * c8 + 2], hh.z, ah2);
            ah3 = fdot2(wo[4 * c8 + 3], hh.w, ah3);
            al0 = fdot2(wo[4 * c8 + 0], hl.x, al0);
            al1 = fdot2(wo[4 * c8 + 1], hl.y, al1);
            al2 = fdot2(wo[4 * c8 + 2], hl.z, al2);
            al3 = fdot2(wo[4 * c8 + 3], hl.w, al3);
            if ((c8 >> 4) == kh) {
                int i = c8 & 15;
                uint4 ow = o_lds4[c8 * 256 + r];
                gh0 = fdot2(wg[4 * i + 0], hh.x, gh0);
                gh1 = fdot2(wg[4 * i + 1], hh.y, gh1);
                gh0 = fdot2(wg[4 * i + 2], hh.z, gh0);
                gh1 = fdot2(wg[4 * i + 3], hh.w, gh1);
                gl0 = fdot2(wg[4 * i + 0], hl.x, gl0);
                gl1 = fdot2(wg[4 * i + 1], hl.y, gl1);
                gl0 = fdot2(wg[4 * i + 2], hl.z, gl0);
                gl1 = fdot2(wg[4 * i + 3], hl.w, gl1);
                oh0 = fdot2(ow.x, hh.x, oh0);
                oh1 = fdot2(ow.y, hh.y, oh1);
                oh0 = fdot2(ow.z, hh.z, oh0);
                oh1 = fdot2(ow.w, hh.w, oh1);
                ol0 = fdot2(ow.x, hl.x, ol0);
                ol1 = fdot2(ow.y, hl.y, ol1);
                ol0 = fdot2(ow.z, hl.z, ol0);
                ol1 = fdot2(ow.w, hl.w, ol1);
            }
        }
        float A = ((ah0 + ah1) + (ah2 + ah3)) + ((al0 + al1) + (al2 + al3)) + xa;
        // i/f are both sigmoid: apply on the owner thread, pre-barrier.
        float Asig = 1.f / (1.f + __expf(-A));
        float Gp = (gh0 + gh1) + (gl0 + gl1);
        float Op = (oh0 + oh1) + (ol0 + ol1);

        sA[tid] = Asig; sG[tid] = Gp; sO[tid] = Op;
        __syncthreads();
        if (tid < H) {
            float iv = sA[tid];
            float fv = sA[H + tid];
            float gv = tanhf(sG[tid] + sG[H + tid] + xgg);
            float ov = 1.f / (1.f + __expf(-(sO[tid] + sO[H + tid] + xgo)));
            c = fv * c + iv * gv;
            float nh = ov * tanhf(c);
            hcur = nh;
            __half hh16 = __float2half(nh);
            hckp[tid] = hh16;
            hhi[tid] = hh16;
            hlo[tid] = __float2half(nh - __half2float(hh16));
        }
        __syncthreads();
        xgp += G4;
        hckp += H;
    }
    if (tid < H) { h_st[b * H + tid] = hcur; c_st[b * H + tid] = c; }
}

// ---------------- logits = h @ W_out^T + b_out, masked with -1 ------------
// 32-timestep tiles (halves Wo L2 re-reads), vectorized f16 h load.
__global__ void k_logits(const __half* __restrict__ hck, const float* __restrict__ Wo,
                         const float* __restrict__ bo, const int* __restrict__ dlen,
                         float* __restrict__ pred, int t0, int Cc) {
    int b = blockIdx.y;
    int ct0 = blockIdx.x * 32;
    if (ct0 >= Cc) return;
    int steps_b = dlen[b];
    int nrow = Cc - ct0; if (nrow > 32) nrow = 32;
    if (t0 + ct0 >= steps_b) {   // whole tile inactive: write -1
        for (int rr = 0; rr < nrow; ++rr) {
            int t = t0 + ct0 + rr;
            if (t >= STEPS) break;
            float* pr = pred + ((size_t)b * STEPS + t) * VOCAB;
            for (int cidx = threadIdx.x; cidx < VOCAB; cidx += 256) pr[cidx] = -1.f;
        }
        return;
    }
    __shared__ __align__(16) float4 a4[32][H / 4];
    float* a = (float*)a4;
    const unsigned* hu = (const unsigned*)hck;
    for (int i = threadIdx.x; i < 32 * (H / 2); i += 256) {
        int rr = i >> 7, k2 = i & 127;
        float2 v = make_float2(0.f, 0.f);
        if (rr < nrow) {
            unsigned hw = hu[((size_t)b * Cc + ct0 + rr) * (H / 2) + k2];
            __half2 h2 = *(const __half2*)&hw;
            v = __half22float2(h2);
        }
        a[rr * H + 2 * k2] = v.x;
        a[rr * H + 2 * k2 + 1] = v.y;
    }
    __syncthreads();
    for (int cidx = threadIdx.x; cidx < VOCAB; cidx += 256) {
        const float4* wr = (const float4*)(Wo + (size_t)cidx * H);
        float acc[32];
        float bv = bo[cidx];
        #pragma unroll
        for (int rr = 0; rr < 32; ++rr) acc[rr] = bv;
        for (int k4 = 0; k4 < H / 4; ++k4) {
            float4 w = wr[k4];
            #pragma unroll
            for (int rr = 0; rr < 32; ++rr) {
                float4 av = a4[rr][k4];
                acc[rr] += av.x * w.x + av.y * w.y + av.z * w.z + av.w * w.w;
            }
        }
        for (int rr = 0; rr < nrow; ++rr) {
            int t = t0 + ct0 + rr;
            if (t >= STEPS) break;
            pred[((size_t)b * STEPS + t) * VOCAB + cidx] = (t < steps_b) ? acc[rr] : -1.f;
        }
    }
}

extern "C" void kernel_launch(void* const* d_in, const int* in_sizes, int n_in,
                              void* d_out, int out_size, void* d_ws, size_t ws_size,
                              hipStream_t stream) {
    const float* enc   = (const float*)d_in[0];
    const float* caps  = (const float*)d_in[1];
    const float* w_ih  = (const float*)d_in[2];
    const float* w_hh  = (const float*)d_in[3];
    const float* b_ih  = (const float*)d_in[4];
    const float* b_hh  = (const float*)d_in[5];
    const float* W_out = (const float*)d_in[6];
    const float* b_out = (const float*)d_in[7];
    const float* W_emb = (const float*)d_in[8];
    const float* b_emb = (const float*)d_in[9];
    const float* W_h   = (const float*)d_in[10];
    const float* b_h   = (const float*)d_in[11];
    const float* W_c   = (const float*)d_in[12];
    const float* b_c   = (const float*)d_in[13];
    const int*   lens  = (const int*)d_in[14];

    float* out_pred = (float*)d_out;
    float* out_caps = out_pred + (size_t)BS * STEPS * VOCAB;
    float* out_dec  = out_caps + (size_t)BS * T * WV;
    float* out_sidx = out_dec + BS;

    char* w = (char*)d_ws;
    size_t off = 0;
    auto take = [&](size_t bytes) -> char* {
        char* p = w + off;
        off += (bytes + 255) & ~(size_t)255;
        return p;
    };
    int*     sidx = (int*)take(BS * 4);
    int*     dlen = (int*)take(BS * 4);
    float*   Wc   = (float*)take((size_t)G4 * WV * 4);
    float*   bc   = (float*)take(G4 * 4);
    float*   h_st = (float*)take((size_t)BS * H * 4);
    float*   c_st = (float*)take((size_t)BS * H * 4);
    __half2* wT   = (__half2*)take((size_t)(H / 2) * G4 * 4);

    size_t rem = (ws_size > off) ? (ws_size - off) : 0;
    size_t per_step = (size_t)BS * G4 * 4 + (size_t)BS * H * 2 + 1024;
    int C = (int)(rem / per_step);
    if (C < 1) C = 1;
    if (C > STEPS) C = STEPS;
    float*  xg  = (float*)take((size_t)BS * C * G4 * 4);
    __half* hck = (__half*)take((size_t)BS * C * H * 2);

    // allow 138 KB dynamic LDS for the recurrent kernel (host-side, capture-safe)
    (void)hipFuncSetAttribute((const void*)k_lstm,
                              hipFuncAttributeMaxDynamicSharedMemorySize, LSTM_SMEM);

    k_sort<<<1, 256, 0, stream>>>(lens, sidx, dlen, out_dec, out_sidx);
    k_gather<<<BS, 256, 0, stream>>>(caps, sidx, out_caps);
    k_wcomb<<<G4 * WV / 256, 256, 0, stream>>>(w_ih, W_emb, Wc);
    k_bcomb<<<G4 / 256, 256, 0, stream>>>(w_ih, b_ih, b_hh, b_emb, bc);
    k_packw<<<(H / 2) * G4 / 256, 256, 0, stream>>>(w_hh, wT);
    k_inithc<<<BS, 256, 0, stream>>>(enc, sidx, W_h, b_h, W_c, b_c, h_st, c_st);

    for (int t0 = 0; t0 < STEPS; t0 += C) {
        int Cc = STEPS - t0; if (Cc > C) Cc = C;
        dim3 g((Cc + 31) / 32, BS);
        k_xg<<<g, 256, 0, stream>>>(out_caps, Wc, bc, dlen, xg, t0, Cc);
        k_lstm<<<BS, 512, LSTM_SMEM, stream>>>(wT, xg, dlen, h_st, c_st, hck, t0, Cc);
        k_logits<<<g, 256, 0, stream>>>(hck, W_out, b_out, dlen, out_pred, t0, Cc);
    }
}

// Round 4
// 6117.639 us; speedup vs baseline: 2.6744x; 2.6744x over previous
//
#include <hip/hip_runtime.h>
#include <hip/hip_fp16.h>

#define BS 256
#define T 256
#define STEPS 255
#define WV 100
#define INP 64
#define H 256
#define G4 1024
#define VOCAB 600

// ---------------- packed f16 dot2 with f32 accumulate ---------------------
typedef _Float16 f16x2 __attribute__((ext_vector_type(2)));

__device__ __forceinline__ float fdot2(unsigned w, unsigned h, float acc) {
#if defined(__has_builtin) && __has_builtin(__builtin_amdgcn_fdot2)
    return __builtin_amdgcn_fdot2(__builtin_bit_cast(f16x2, w),
                                  __builtin_bit_cast(f16x2, h), acc, false);
#else
    __half2 wv = *(const __half2*)&w;
    __half2 hv = *(const __half2*)&h;
    float2 wf = __half22float2(wv), hf = __half22float2(hv);
    return acc + wf.x * hf.x + wf.y * hf.y;
#endif
}

// ---------------- sort: stable descending by length (jax argsort(-len)) ----
__global__ void k_sort(const int* __restrict__ lens, int* __restrict__ sidx,
                       int* __restrict__ dlen, float* __restrict__ out_dec,
                       float* __restrict__ out_sidx) {
    __shared__ int L[BS];
    int i = threadIdx.x;
    L[i] = lens[i];
    __syncthreads();
    int li = L[i];
    int r = 0;
    for (int j = 0; j < BS; ++j) {
        int lj = L[j];
        r += (lj > li) || (lj == li && j < i);
    }
    sidx[r] = i;
    dlen[r] = li - 1;
    out_sidx[r] = (float)i;
    out_dec[r]  = (float)(li - 1);
}

// ---------------- gather sorted captions to output ------------------------
__global__ void k_gather(const float* __restrict__ cin, const int* __restrict__ sidx,
                         float* __restrict__ cout) {
    int b = blockIdx.x;
    int src = sidx[b];
    const float4* in  = (const float4*)(cin + (size_t)src * T * WV);
    float4* out       = (float4*)(cout + (size_t)b * T * WV);
    for (int i = threadIdx.x; i < T * WV / 4; i += 256) out[i] = in[i];
}

// ---------------- W_comb = w_ih @ W_emb^T  [1024 x 100] -------------------
__global__ void k_wcomb(const float* __restrict__ w_ih, const float* __restrict__ W_emb,
                        float* __restrict__ Wc) {
    int idx = blockIdx.x * 256 + threadIdx.x;   // 102400 threads
    int r = idx / WV, cc = idx % WV;
    float acc = 0.f;
    for (int k = 0; k < INP; ++k) acc += w_ih[r * INP + k] * W_emb[k * WV + cc];
    Wc[idx] = acc;
}

// ---------------- b_comb = b_ih + b_hh + w_ih @ b_emb ---------------------
__global__ void k_bcomb(const float* __restrict__ w_ih, const float* __restrict__ b_ih,
                        const float* __restrict__ b_hh, const float* __restrict__ b_emb,
                        float* __restrict__ bc) {
    int r = blockIdx.x * 256 + threadIdx.x;     // 1024 threads
    float acc = b_ih[r] + b_hh[r];
    for (int k = 0; k < INP; ++k) acc += w_ih[r * INP + k] * b_emb[k];
    bc[r] = acc;
}

// ---------------- pack w_hh -> fp16, k-major transposed -------------------
// wT[k2*1024 + r] = half2(w_hh[r][2k2], w_hh[r][2k2+1])
__global__ void k_packw(const float* __restrict__ w_hh, __half2* __restrict__ wT) {
    int idx = blockIdx.x * 256 + threadIdx.x;   // 131072 threads
    int k2 = idx >> 10, r = idx & 1023;
    wT[(size_t)k2 * G4 + r] =
        __floats2half2_rn(w_hh[(size_t)r * H + 2 * k2], w_hh[(size_t)r * H + 2 * k2 + 1]);
}

// ---------------- h0 = enc@W_h^T + b_h ; c0 = enc@W_c^T + b_c -------------
__global__ void k_inithc(const float* __restrict__ enc, const int* __restrict__ sidx,
                         const float* __restrict__ W_h, const float* __restrict__ b_h,
                         const float* __restrict__ W_c, const float* __restrict__ b_c,
                         float* __restrict__ h_st, float* __restrict__ c_st) {
    int b = blockIdx.x, j = threadIdx.x;
    __shared__ __align__(16) float e[INP];
    int src = sidx[b];
    if (j < INP) e[j] = enc[src * INP + j];
    __syncthreads();
    const float4* e4  = (const float4*)e;
    const float4* wh4 = (const float4*)(W_h + (size_t)j * INP);
    const float4* wc4 = (const float4*)(W_c + (size_t)j * INP);
    float ah = b_h[j], ac = b_c[j];
    #pragma unroll
    for (int k4 = 0; k4 < INP / 4; ++k4) {
        float4 ev = e4[k4];
        float4 wh = wh4[k4];
        float4 wc = wc4[k4];
        ah += ev.x * wh.x + ev.y * wh.y + ev.z * wh.z + ev.w * wh.w;
        ac += ev.x * wc.x + ev.y * wc.y + ev.z * wc.z + ev.w * wc.w;
    }
    h_st[b * H + j] = ah;
    c_st[b * H + j] = ac;
}

// ---------------- xg[b,ct,:] = caps_sorted[b,t,:] @ W_comb^T + b_comb -----
// 16-row tiles: acc[16] stays in registers (acc[32] spilled to scratch,
// round-3 regression: 20 GB/dispatch scratch traffic).
__global__ void k_xg(const float* __restrict__ caps, const float* __restrict__ Wc,
                     const float* __restrict__ bc, const int* __restrict__ dlen,
                     float* __restrict__ xg, int t0, int Cc) {
    int b = blockIdx.y;
    int ct0 = blockIdx.x * 16;
    if (t0 + ct0 >= dlen[b]) return;   // rows never consumed by the LSTM
    __shared__ __align__(16) float4 cs4[16][WV / 4];   // 16 timesteps x 100
    float* cs = (float*)cs4;
    for (int i = threadIdx.x; i < 16 * WV; i += 256) {
        int rr = i / WV, k = i % WV;
        int t = t0 + ct0 + rr;
        cs[rr * WV + k] = (t < T && ct0 + rr < Cc) ? caps[((size_t)b * T + t) * WV + k] : 0.f;
    }
    __syncthreads();
    int nrow = Cc - ct0; if (nrow > 16) nrow = 16;
    for (int rq = 0; rq < 4; ++rq) {
        int r = threadIdx.x + rq * 256;
        float acc[16];
        float bv = bc[r];
        #pragma unroll
        for (int rr = 0; rr < 16; ++rr) acc[rr] = bv;
        const float4* wr = (const float4*)(Wc + (size_t)r * WV);
        for (int k4 = 0; k4 < WV / 4; ++k4) {
            float4 w = wr[k4];
            #pragma unroll
            for (int rr = 0; rr < 16; ++rr) {
                float4 av = cs4[rr][k4];
                acc[rr] += av.x * w.x + av.y * w.y + av.z * w.z + av.w * w.w;
            }
        }
        for (int rr = 0; rr < nrow; ++rr)
            xg[((size_t)b * Cc + ct0 + rr) * G4 + r] = acc[rr];
    }
}

// ---------------- recurrent LSTM core: one block per batch row ------------
// 512 threads, ALL w_hh weights on-chip:
//   rows 0..511 (i,f): thread t holds row t in regs      (128 half2 dwords)
//   rows 512..767 (g): pair (j, j+256) split K-halves    ( 64 half2 dwords)
//   rows 768..1023(o): LDS, uint4-packed [c8][256]       (128 KB, b128 reads)
// h broadcast from LDS as hi/lo f16 split (error ~= f32-h path).
// Merged loop: g/o dots reuse the own-row h-chunks -> 80 LDS insts/step
// (was 160: 96 b128 + 64 b32). Identical dot pairing => bitwise-same sums.
#define LSTM_SMEM (131072 + 3 * 512 * 4 + 2 * 256 * 2)   // 138240 B

__global__ __launch_bounds__(512, 1) void k_lstm(const __half2* __restrict__ wT,
        const float* __restrict__ xg, const int* __restrict__ dlen,
        float* __restrict__ h_st, float* __restrict__ c_st,
        __half* __restrict__ hck, int t0, int Cc) {
    extern __shared__ __align__(16) char smem[];
    uint4* o_lds4 = (uint4*)smem;                       // [32][256] uint4 (k2 quads)
    float* sA = (float*)(smem + 131072);                // 512: i/f sigmoids
    float* sG = sA + 512;                               // 512: g partials
    float* sO = sG + 512;                               // 512: o partials
    __half* hhi = (__half*)(sO + 512);                  // 256 (16B aligned)
    __half* hlo = hhi + 256;                            // 256

    int b = blockIdx.x, tid = threadIdx.x;
    int steps_b = dlen[b];
    if (t0 >= steps_b) return;

    const unsigned* wTu = (const unsigned*)wT;
    int r  = tid & 255;
    int kh = __builtin_amdgcn_readfirstlane(tid >> 8);  // wave-uniform K-half

    // ---- preload all recurrent weights on-chip (once per launch) ----
    unsigned wo[128];             // own row `tid` (i for tid<256, f else)
    #pragma unroll
    for (int k2 = 0; k2 < 128; ++k2) wo[k2] = wTu[k2 * G4 + tid];
    unsigned wg[64];              // g-row 512+r, K-half kh
    #pragma unroll
    for (int i = 0; i < 64; ++i) wg[i] = wTu[(kh * 64 + i) * G4 + 512 + r];
    for (int i = tid; i < 32 * 256; i += 512) {         // o rows -> LDS uint4-packed
        int c8 = i >> 8, rr = i & 255;
        uint4 v;
        v.x = wTu[(4 * c8 + 0) * G4 + 768 + rr];
        v.y = wTu[(4 * c8 + 1) * G4 + 768 + rr];
        v.z = wTu[(4 * c8 + 2) * G4 + 768 + rr];
        v.w = wTu[(4 * c8 + 3) * G4 + 768 + rr];
        o_lds4[i] = v;
    }

    float c = 0.f, hcur = 0.f;
    if (tid < H) {
        hcur = h_st[b * H + tid];
        c    = c_st[b * H + tid];
        __half hh16 = __float2half(hcur);
        hhi[tid] = hh16;
        hlo[tid] = __float2half(hcur - __half2float(hh16));
    }
    __syncthreads();

    const uint4* hhi4 = (const uint4*)hhi;   // 4 half2 per read (broadcast)
    const uint4* hlo4 = (const uint4*)hlo;
    int tend = t0 + Cc; if (tend > steps_b) tend = steps_b;
    const float* xgp = xg + (size_t)b * Cc * G4;
    __half* hckp = hck + (size_t)b * Cc * H;

    for (int t = t0; t < tend; ++t) {
        float xa = xgp[tid];                 // consumed after dot phase
        float xgg = 0.f, xgo = 0.f;
        if (tid < H) { xgg = xgp[512 + tid]; xgo = xgp[768 + tid]; }

        // ---- merged loop: own i/f full-K dots; g/o dots piggyback on the
        //      matching h-chunks (wave-uniform branch, no divergence) ----
        float ah0 = 0.f, ah1 = 0.f, ah2 = 0.f, ah3 = 0.f;
        float al0 = 0.f, al1 = 0.f, al2 = 0.f, al3 = 0.f;
        float gh0 = 0.f, gh1 = 0.f, gl0 = 0.f, gl1 = 0.f;
        float oh0 = 0.f, oh1 = 0.f, ol0 = 0.f, ol1 = 0.f;
        #pragma unroll
        for (int c8 = 0; c8 < 32; ++c8) {
            uint4 hh = hhi4[c8];
            uint4 hl = hlo4[c8];
            ah0 = fdot2(wo[4 * c8 + 0], hh.x, ah0);
            ah1 = fdot2(wo[4 * c8 + 1], hh.y, ah1);
            ah2 = fdot2(wo[4 * c8 + 2], hh.z, ah2);
            ah3 = fdot2(wo[4 * c8 + 3], hh.w, ah3);
            al0 = fdot2(wo[4 * c8 + 0], hl.x, al0);
            al1 = fdot2(wo[4 * c8 + 1], hl.y, al1);
            al2 = fdot2(wo[4 * c8 + 2], hl.z, al2);
            al3 = fdot2(wo[4 * c8 + 3], hl.w, al3);
            if ((c8 >> 4) == kh) {
                int i = c8 & 15;
                uint4 ow = o_lds4[c8 * 256 + r];
                gh0 = fdot2(wg[4 * i + 0], hh.x, gh0);
                gh1 = fdot2(wg[4 * i + 1], hh.y, gh1);
                gh0 = fdot2(wg[4 * i + 2], hh.z, gh0);
                gh1 = fdot2(wg[4 * i + 3], hh.w, gh1);
                gl0 = fdot2(wg[4 * i + 0], hl.x, gl0);
                gl1 = fdot2(wg[4 * i + 1], hl.y, gl1);
                gl0 = fdot2(wg[4 * i + 2], hl.z, gl0);
                gl1 = fdot2(wg[4 * i + 3], hl.w, gl1);
                oh0 = fdot2(ow.x, hh.x, oh0);
                oh1 = fdot2(ow.y, hh.y, oh1);
                oh0 = fdot2(ow.z, hh.z, oh0);
                oh1 = fdot2(ow.w, hh.w, oh1);
                ol0 = fdot2(ow.x, hl.x, ol0);
                ol1 = fdot2(ow.y, hl.y, ol1);
                ol0 = fdot2(ow.z, hl.z, ol0);
                ol1 = fdot2(ow.w, hl.w, ol1);
            }
        }
        float A = ((ah0 + ah1) + (ah2 + ah3)) + ((al0 + al1) + (al2 + al3)) + xa;
        // i/f are both sigmoid: apply on the owner thread, pre-barrier.
        float Asig = 1.f / (1.f + __expf(-A));
        float Gp = (gh0 + gh1) + (gl0 + gl1);
        float Op = (oh0 + oh1) + (ol0 + ol1);

        sA[tid] = Asig; sG[tid] = Gp; sO[tid] = Op;
        __syncthreads();
        if (tid < H) {
            float iv = sA[tid];
            float fv = sA[H + tid];
            float gv = tanhf(sG[tid] + sG[H + tid] + xgg);
            float ov = 1.f / (1.f + __expf(-(sO[tid] + sO[H + tid] + xgo)));
            c = fv * c + iv * gv;
            float nh = ov * tanhf(c);
            hcur = nh;
            __half hh16 = __float2half(nh);
            hckp[tid] = hh16;
            hhi[tid] = hh16;
            hlo[tid] = __float2half(nh - __half2float(hh16));
        }
        __syncthreads();
        xgp += G4;
        hckp += H;
    }
    if (tid < H) { h_st[b * H + tid] = hcur; c_st[b * H + tid] = c; }
}

// ---------------- logits = h @ W_out^T + b_out, masked with -1 ------------
// 16-row tiles: acc[16] stays in registers (32-row variant spilled).
__global__ void k_logits(const __half* __restrict__ hck, const float* __restrict__ Wo,
                         const float* __restrict__ bo, const int* __restrict__ dlen,
                         float* __restrict__ pred, int t0, int Cc) {
    int b = blockIdx.y;
    int ct0 = blockIdx.x * 16;
    if (ct0 >= Cc) return;
    int steps_b = dlen[b];
    int nrow = Cc - ct0; if (nrow > 16) nrow = 16;
    if (t0 + ct0 >= steps_b) {   // whole tile inactive: write -1
        for (int rr = 0; rr < nrow; ++rr) {
            int t = t0 + ct0 + rr;
            if (t >= STEPS) break;
            float* pr = pred + ((size_t)b * STEPS + t) * VOCAB;
            for (int cidx = threadIdx.x; cidx < VOCAB; cidx += 256) pr[cidx] = -1.f;
        }
        return;
    }
    __shared__ __align__(16) float4 a4[16][H / 4];
    float* a = (float*)a4;
    for (int i = threadIdx.x; i < 16 * H; i += 256) {
        int rr = i >> 8, k = i & 255;
        float v = (rr < nrow) ? __half2float(hck[((size_t)b * Cc + ct0 + rr) * H + k]) : 0.f;
        a[rr * H + k] = v;
    }
    __syncthreads();
    for (int cidx = threadIdx.x; cidx < VOCAB; cidx += 256) {
        const float4* wr = (const float4*)(Wo + (size_t)cidx * H);
        float acc[16];
        float bv = bo[cidx];
        #pragma unroll
        for (int rr = 0; rr < 16; ++rr) acc[rr] = bv;
        for (int k4 = 0; k4 < H / 4; ++k4) {
            float4 w = wr[k4];
            #pragma unroll
            for (int rr = 0; rr < 16; ++rr) {
                float4 av = a4[rr][k4];
                acc[rr] += av.x * w.x + av.y * w.y + av.z * w.z + av.w * w.w;
            }
        }
        for (int rr = 0; rr < nrow; ++rr) {
            int t = t0 + ct0 + rr;
            if (t >= STEPS) break;
            pred[((size_t)b * STEPS + t) * VOCAB + cidx] = (t < steps_b) ? acc[rr] : -1.f;
        }
    }
}

extern "C" void kernel_launch(void* const* d_in, const int* in_sizes, int n_in,
                              void* d_out, int out_size, void* d_ws, size_t ws_size,
                              hipStream_t stream) {
    const float* enc   = (const float*)d_in[0];
    const float* caps  = (const float*)d_in[1];
    const float* w_ih  = (const float*)d_in[2];
    const float* w_hh  = (const float*)d_in[3];
    const float* b_ih  = (const float*)d_in[4];
    const float* b_hh  = (const float*)d_in[5];
    const float* W_out = (const float*)d_in[6];
    const float* b_out = (const float*)d_in[7];
    const float* W_emb = (const float*)d_in[8];
    const float* b_emb = (const float*)d_in[9];
    const float* W_h   = (const float*)d_in[10];
    const float* b_h   = (const float*)d_in[11];
    const float* W_c   = (const float*)d_in[12];
    const float* b_c   = (const float*)d_in[13];
    const int*   lens  = (const int*)d_in[14];

    float* out_pred = (float*)d_out;
    float* out_caps = out_pred + (size_t)BS * STEPS * VOCAB;
    float* out_dec  = out_caps + (size_t)BS * T * WV;
    float* out_sidx = out_dec + BS;

    char* w = (char*)d_ws;
    size_t off = 0;
    auto take = [&](size_t bytes) -> char* {
        char* p = w + off;
        off += (bytes + 255) & ~(size_t)255;
        return p;
    };
    int*     sidx = (int*)take(BS * 4);
    int*     dlen = (int*)take(BS * 4);
    float*   Wc   = (float*)take((size_t)G4 * WV * 4);
    float*   bc   = (float*)take(G4 * 4);
    float*   h_st = (float*)take((size_t)BS * H * 4);
    float*   c_st = (float*)take((size_t)BS * H * 4);
    __half2* wT   = (__half2*)take((size_t)(H / 2) * G4 * 4);

    size_t rem = (ws_size > off) ? (ws_size - off) : 0;
    size_t per_step = (size_t)BS * G4 * 4 + (size_t)BS * H * 2 + 1024;
    int C = (int)(rem / per_step);
    if (C < 1) C = 1;
    if (C > STEPS) C = STEPS;
    float*  xg  = (float*)take((size_t)BS * C * G4 * 4);
    __half* hck = (__half*)take((size_t)BS * C * H * 2);

    // allow 138 KB dynamic LDS for the recurrent kernel (host-side, capture-safe)
    (void)hipFuncSetAttribute((const void*)k_lstm,
                              hipFuncAttributeMaxDynamicSharedMemorySize, LSTM_SMEM);

    k_sort<<<1, 256, 0, stream>>>(lens, sidx, dlen, out_dec, out_sidx);
    k_gather<<<BS, 256, 0, stream>>>(caps, sidx, out_caps);
    k_wcomb<<<G4 * WV / 256, 256, 0, stream>>>(w_ih, W_emb, Wc);
    k_bcomb<<<G4 / 256, 256, 0, stream>>>(w_ih, b_ih, b_hh, b_emb, bc);
    k_packw<<<(H / 2) * G4 / 256, 256, 0, stream>>>(w_hh, wT);
    k_inithc<<<BS, 256, 0, stream>>>(enc, sidx, W_h, b_h, W_c, b_c, h_st, c_st);

    for (int t0 = 0; t0 < STEPS; t0 += C) {
        int Cc = STEPS - t0; if (Cc > C) Cc = C;
        dim3 g((Cc + 15) / 16, BS);
        k_xg<<<g, 256, 0, stream>>>(out_caps, Wc, bc, dlen, xg, t0, Cc);
        k_lstm<<<BS, 512, LSTM_SMEM, stream>>>(wT, xg, dlen, h_st, c_st, hck, t0, Cc);
        k_logits<<<g, 256, 0, stream>>>(hck, W_out, b_out, dlen, out_pred, t0, Cc);
    }
}

// Round 5
// 2082.442 us; speedup vs baseline: 7.8568x; 2.9377x over previous
//
#include <hip/hip_runtime.h>
#include <hip/hip_fp16.h>

#define BS 256
#define T 256
#define STEPS 255
#define WV 100
#define INP 64
#define H 256
#define G4 1024
#define VOCAB 600

// ---------------- packed f16 dot2 with f32 accumulate ---------------------
typedef _Float16 f16x2 __attribute__((ext_vector_type(2)));

__device__ __forceinline__ float fdot2(unsigned w, unsigned h, float acc) {
#if defined(__has_builtin) && __has_builtin(__builtin_amdgcn_fdot2)
    return __builtin_amdgcn_fdot2(__builtin_bit_cast(f16x2, w),
                                  __builtin_bit_cast(f16x2, h), acc, false);
#else
    __half2 wv = *(const __half2*)&w;
    __half2 hv = *(const __half2*)&h;
    float2 wf = __half22float2(wv), hf = __half22float2(hv);
    return acc + wf.x * hf.x + wf.y * hf.y;
#endif
}

// ---------------- sort: stable descending by length (jax argsort(-len)) ----
__global__ void k_sort(const int* __restrict__ lens, int* __restrict__ sidx,
                       int* __restrict__ dlen, float* __restrict__ out_dec,
                       float* __restrict__ out_sidx) {
    __shared__ int L[BS];
    int i = threadIdx.x;
    L[i] = lens[i];
    __syncthreads();
    int li = L[i];
    int r = 0;
    for (int j = 0; j < BS; ++j) {
        int lj = L[j];
        r += (lj > li) || (lj == li && j < i);
    }
    sidx[r] = i;
    dlen[r] = li - 1;
    out_sidx[r] = (float)i;
    out_dec[r]  = (float)(li - 1);
}

// ---------------- gather sorted captions to output ------------------------
__global__ void k_gather(const float* __restrict__ cin, const int* __restrict__ sidx,
                         float* __restrict__ cout) {
    int b = blockIdx.x;
    int src = sidx[b];
    const float4* in  = (const float4*)(cin + (size_t)src * T * WV);
    float4* out       = (float4*)(cout + (size_t)b * T * WV);
    for (int i = threadIdx.x; i < T * WV / 4; i += 256) out[i] = in[i];
}

// ---------------- W_comb = w_ih @ W_emb^T  [1024 x 100] -------------------
__global__ void k_wcomb(const float* __restrict__ w_ih, const float* __restrict__ W_emb,
                        float* __restrict__ Wc) {
    int idx = blockIdx.x * 256 + threadIdx.x;   // 102400 threads
    int r = idx / WV, cc = idx % WV;
    float acc = 0.f;
    for (int k = 0; k < INP; ++k) acc += w_ih[r * INP + k] * W_emb[k * WV + cc];
    Wc[idx] = acc;
}

// ---------------- b_comb = b_ih + b_hh + w_ih @ b_emb ---------------------
__global__ void k_bcomb(const float* __restrict__ w_ih, const float* __restrict__ b_ih,
                        const float* __restrict__ b_hh, const float* __restrict__ b_emb,
                        float* __restrict__ bc) {
    int r = blockIdx.x * 256 + threadIdx.x;     // 1024 threads
    float acc = b_ih[r] + b_hh[r];
    for (int k = 0; k < INP; ++k) acc += w_ih[r * INP + k] * b_emb[k];
    bc[r] = acc;
}

// ---------------- pack w_hh -> fp16, k-major transposed -------------------
// wT[k2*1024 + r] = half2(w_hh[r][2k2], w_hh[r][2k2+1])
__global__ void k_packw(const float* __restrict__ w_hh, __half2* __restrict__ wT) {
    int idx = blockIdx.x * 256 + threadIdx.x;   // 131072 threads
    int k2 = idx >> 10, r = idx & 1023;
    wT[(size_t)k2 * G4 + r] =
        __floats2half2_rn(w_hh[(size_t)r * H + 2 * k2], w_hh[(size_t)r * H + 2 * k2 + 1]);
}

// ---------------- h0 = enc@W_h^T + b_h ; c0 = enc@W_c^T + b_c -------------
__global__ void k_inithc(const float* __restrict__ enc, const int* __restrict__ sidx,
                         const float* __restrict__ W_h, const float* __restrict__ b_h,
                         const float* __restrict__ W_c, const float* __restrict__ b_c,
                         float* __restrict__ h_st, float* __restrict__ c_st) {
    int b = blockIdx.x, j = threadIdx.x;
    __shared__ __align__(16) float e[INP];
    int src = sidx[b];
    if (j < INP) e[j] = enc[src * INP + j];
    __syncthreads();
    const float4* e4  = (const float4*)e;
    const float4* wh4 = (const float4*)(W_h + (size_t)j * INP);
    const float4* wc4 = (const float4*)(W_c + (size_t)j * INP);
    float ah = b_h[j], ac = b_c[j];
    #pragma unroll
    for (int k4 = 0; k4 < INP / 4; ++k4) {
        float4 ev = e4[k4];
        float4 wh = wh4[k4];
        float4 wc = wc4[k4];
        ah += ev.x * wh.x + ev.y * wh.y + ev.z * wh.z + ev.w * wh.w;
        ac += ev.x * wc.x + ev.y * wc.y + ev.z * wc.z + ev.w * wc.w;
    }
    h_st[b * H + j] = ah;
    c_st[b * H + j] = ac;
}

// ---------------- xg[b,ct,:] = caps_sorted[b,t,:] @ W_comb^T + b_comb -----
// 16-row tiles: acc[16] stays in registers (acc[32] spilled -> 20 GB scratch).
__global__ void k_xg(const float* __restrict__ caps, const float* __restrict__ Wc,
                     const float* __restrict__ bc, const int* __restrict__ dlen,
                     float* __restrict__ xg, int t0, int Cc) {
    int b = blockIdx.y;
    int ct0 = blockIdx.x * 16;
    if (t0 + ct0 >= dlen[b]) return;   // rows never consumed by the LSTM
    __shared__ __align__(16) float4 cs4[16][WV / 4];   // 16 timesteps x 100
    float* cs = (float*)cs4;
    for (int i = threadIdx.x; i < 16 * WV; i += 256) {
        int rr = i / WV, k = i % WV;
        int t = t0 + ct0 + rr;
        cs[rr * WV + k] = (t < T && ct0 + rr < Cc) ? caps[((size_t)b * T + t) * WV + k] : 0.f;
    }
    __syncthreads();
    int nrow = Cc - ct0; if (nrow > 16) nrow = 16;
    for (int rq = 0; rq < 4; ++rq) {
        int r = threadIdx.x + rq * 256;
        float acc[16];
        float bv = bc[r];
        #pragma unroll
        for (int rr = 0; rr < 16; ++rr) acc[rr] = bv;
        const float4* wr = (const float4*)(Wc + (size_t)r * WV);
        for (int k4 = 0; k4 < WV / 4; ++k4) {
            float4 w = wr[k4];
            #pragma unroll
            for (int rr = 0; rr < 16; ++rr) {
                float4 av = cs4[rr][k4];
                acc[rr] += av.x * w.x + av.y * w.y + av.z * w.z + av.w * w.w;
            }
        }
        for (int rr = 0; rr < nrow; ++rr)
            xg[((size_t)b * Cc + ct0 + rr) * G4 + r] = acc[rr];
    }
}

// ---------------- recurrent LSTM core: one block per batch row ------------
// 512 threads, ALL w_hh weights on-chip:
//   rows 0..511 (i,f): thread t holds row t in regs, REORDERED:
//       wo_m[64] = my-K-half chunk dwords, wo_o[64] = other half
//   rows 512..767 (g): pair (j, j+256) split K-halves    (wg[64])
//   rows 768..1023(o): LDS, uint4-packed [c8][256]       (128 KB, b128 reads)
// h broadcast from LDS as hi/lo f16 split (error ~= f32-h path).
// Static two-phase K loop: phase 1 = other-half chunks, i/f dots only;
// phase 2 = my-half chunks, i/f + g + o dots off ONE h-read. All register
// indices compile-time (rule #20); only LDS addresses are runtime.
// amdgpu_waves_per_eu(2,2): LDS forces 1 block/CU = 2 waves/SIMD, so 256
// VGPRs/lane are legal -> 192 persistent weight dwords stay in VGPRs
// (without this the allocator clamps to 128 and spills; round-3/4 showed
// 6.9 GB/dispatch scratch FETCH).
#define LSTM_SMEM (131072 + 3 * 512 * 4 + 2 * 256 * 2)   // 138240 B

__global__ __launch_bounds__(512)
__attribute__((amdgpu_waves_per_eu(2, 2)))
void k_lstm(const __half2* __restrict__ wT,
        const float* __restrict__ xg, const int* __restrict__ dlen,
        float* __restrict__ h_st, float* __restrict__ c_st,
        __half* __restrict__ hck, int t0, int Cc) {
    extern __shared__ __align__(16) char smem[];
    uint4* o_lds4 = (uint4*)smem;                       // [32][256] uint4 (k2 quads)
    float* sA = (float*)(smem + 131072);                // 512: i/f sigmoids
    float* sG = sA + 512;                               // 512: g partials
    float* sO = sG + 512;                               // 512: o partials
    __half* hhi = (__half*)(sO + 512);                  // 256 (16B aligned)
    __half* hlo = hhi + 256;                            // 256

    int b = blockIdx.x, tid = threadIdx.x;
    int steps_b = dlen[b];
    if (t0 >= steps_b) return;

    const unsigned* wTu = (const unsigned*)wT;
    int r  = tid & 255;
    int kh = __builtin_amdgcn_readfirstlane(tid >> 8);  // wave-uniform K-half
    int myc = kh * 16;          // my chunk base
    int otc = 16 - myc;         // other chunk base

    // ---- preload all recurrent weights on-chip (once per launch) ----
    unsigned wo_m[64], wo_o[64];  // own row `tid` (i for tid<256, f else)
    #pragma unroll
    for (int i = 0; i < 64; ++i) wo_m[i] = wTu[(myc * 4 + i) * G4 + tid];
    #pragma unroll
    for (int i = 0; i < 64; ++i) wo_o[i] = wTu[(otc * 4 + i) * G4 + tid];
    unsigned wg[64];              // g-row 512+r, my K-half
    #pragma unroll
    for (int i = 0; i < 64; ++i) wg[i] = wTu[(myc * 4 + i) * G4 + 512 + r];
    for (int i = tid; i < 32 * 256; i += 512) {         // o rows -> LDS uint4-packed
        int c8 = i >> 8, rr = i & 255;
        uint4 v;
        v.x = wTu[(4 * c8 + 0) * G4 + 768 + rr];
        v.y = wTu[(4 * c8 + 1) * G4 + 768 + rr];
        v.z = wTu[(4 * c8 + 2) * G4 + 768 + rr];
        v.w = wTu[(4 * c8 + 3) * G4 + 768 + rr];
        o_lds4[i] = v;
    }

    float c = 0.f, hcur = 0.f;
    if (tid < H) {
        hcur = h_st[b * H + tid];
        c    = c_st[b * H + tid];
        __half hh16 = __float2half(hcur);
        hhi[tid] = hh16;
        hlo[tid] = __float2half(hcur - __half2float(hh16));
    }
    __syncthreads();

    const uint4* hhi4 = (const uint4*)hhi;   // 4 half2 per read (broadcast)
    const uint4* hlo4 = (const uint4*)hlo;
    int tend = t0 + Cc; if (tend > steps_b) tend = steps_b;
    const float* xgp = xg + (size_t)b * Cc * G4;
    __half* hckp = hck + (size_t)b * Cc * H;

    for (int t = t0; t < tend; ++t) {
        float xa = xgp[tid];                 // consumed after dot phase
        float xgg = 0.f, xgo = 0.f;
        if (tid < H) { xgg = xgp[512 + tid]; xgo = xgp[768 + tid]; }

        float ah0 = 0.f, ah1 = 0.f, ah2 = 0.f, ah3 = 0.f;
        float al0 = 0.f, al1 = 0.f, al2 = 0.f, al3 = 0.f;
        float gh0 = 0.f, gh1 = 0.f, gl0 = 0.f, gl1 = 0.f;
        float oh0 = 0.f, oh1 = 0.f, ol0 = 0.f, ol1 = 0.f;

        // ---- phase 1: other-half chunks, own i/f dots only ----
        #pragma unroll
        for (int i = 0; i < 16; ++i) {
            int co = otc + i;
            uint4 hh = hhi4[co];
            uint4 hl = hlo4[co];
            ah0 = fdot2(wo_o[4 * i + 0], hh.x, ah0);
            ah1 = fdot2(wo_o[4 * i + 1], hh.y, ah1);
            ah2 = fdot2(wo_o[4 * i + 2], hh.z, ah2);
            ah3 = fdot2(wo_o[4 * i + 3], hh.w, ah3);
            al0 = fdot2(wo_o[4 * i + 0], hl.x, al0);
            al1 = fdot2(wo_o[4 * i + 1], hl.y, al1);
            al2 = fdot2(wo_o[4 * i + 2], hl.z, al2);
            al3 = fdot2(wo_o[4 * i + 3], hl.w, al3);
        }
        // ---- phase 2: my-half chunks, i/f + g + o dots off one h-read ----
        #pragma unroll
        for (int i = 0; i < 16; ++i) {
            int cm = myc + i;
            uint4 hh = hhi4[cm];
            uint4 hl = hlo4[cm];
            uint4 ow = o_lds4[cm * 256 + r];
            ah0 = fdot2(wo_m[4 * i + 0], hh.x, ah0);
            ah1 = fdot2(wo_m[4 * i + 1], hh.y, ah1);
            ah2 = fdot2(wo_m[4 * i + 2], hh.z, ah2);
            ah3 = fdot2(wo_m[4 * i + 3], hh.w, ah3);
            al0 = fdot2(wo_m[4 * i + 0], hl.x, al0);
            al1 = fdot2(wo_m[4 * i + 1], hl.y, al1);
            al2 = fdot2(wo_m[4 * i + 2], hl.z, al2);
            al3 = fdot2(wo_m[4 * i + 3], hl.w, al3);
            gh0 = fdot2(wg[4 * i + 0], hh.x, gh0);
            gh1 = fdot2(wg[4 * i + 1], hh.y, gh1);
            gh0 = fdot2(wg[4 * i + 2], hh.z, gh0);
            gh1 = fdot2(wg[4 * i + 3], hh.w, gh1);
            gl0 = fdot2(wg[4 * i + 0], hl.x, gl0);
            gl1 = fdot2(wg[4 * i + 1], hl.y, gl1);
            gl0 = fdot2(wg[4 * i + 2], hl.z, gl0);
            gl1 = fdot2(wg[4 * i + 3], hl.w, gl1);
            oh0 = fdot2(ow.x, hh.x, oh0);
            oh1 = fdot2(ow.y, hh.y, oh1);
            oh0 = fdot2(ow.z, hh.z, oh0);
            oh1 = fdot2(ow.w, hh.w, oh1);
            ol0 = fdot2(ow.x, hl.x, ol0);
            ol1 = fdot2(ow.y, hl.y, ol1);
            ol0 = fdot2(ow.z, hl.z, ol0);
            ol1 = fdot2(ow.w, hl.w, ol1);
        }
        float A = ((ah0 + ah1) + (ah2 + ah3)) + ((al0 + al1) + (al2 + al3)) + xa;
        // i/f are both sigmoid: apply on the owner thread, pre-barrier.
        float Asig = 1.f / (1.f + __expf(-A));
        float Gp = (gh0 + gh1) + (gl0 + gl1);
        float Op = (oh0 + oh1) + (ol0 + ol1);

        sA[tid] = Asig; sG[tid] = Gp; sO[tid] = Op;
        __syncthreads();
        if (tid < H) {
            float iv = sA[tid];
            float fv = sA[H + tid];
            float gv = tanhf(sG[tid] + sG[H + tid] + xgg);
            float ov = 1.f / (1.f + __expf(-(sO[tid] + sO[H + tid] + xgo)));
            c = fv * c + iv * gv;
            float nh = ov * tanhf(c);
            hcur = nh;
            __half hh16 = __float2half(nh);
            hckp[tid] = hh16;
            hhi[tid] = hh16;
            hlo[tid] = __float2half(nh - __half2float(hh16));
        }
        __syncthreads();
        xgp += G4;
        hckp += H;
    }
    if (tid < H) { h_st[b * H + tid] = hcur; c_st[b * H + tid] = c; }
}

// ---------------- logits = h @ W_out^T + b_out, masked with -1 ------------
// 16-row tiles: acc[16] stays in registers (32-row variant spilled).
__global__ void k_logits(const __half* __restrict__ hck, const float* __restrict__ Wo,
                         const float* __restrict__ bo, const int* __restrict__ dlen,
                         float* __restrict__ pred, int t0, int Cc) {
    int b = blockIdx.y;
    int ct0 = blockIdx.x * 16;
    if (ct0 >= Cc) return;
    int steps_b = dlen[b];
    int nrow = Cc - ct0; if (nrow > 16) nrow = 16;
    if (t0 + ct0 >= steps_b) {   // whole tile inactive: write -1
        for (int rr = 0; rr < nrow; ++rr) {
            int t = t0 + ct0 + rr;
            if (t >= STEPS) break;
            float* pr = pred + ((size_t)b * STEPS + t) * VOCAB;
            for (int cidx = threadIdx.x; cidx < VOCAB; cidx += 256) pr[cidx] = -1.f;
        }
        return;
    }
    __shared__ __align__(16) float4 a4[16][H / 4];
    float* a = (float*)a4;
    for (int i = threadIdx.x; i < 16 * H; i += 256) {
        int rr = i >> 8, k = i & 255;
        float v = (rr < nrow) ? __half2float(hck[((size_t)b * Cc + ct0 + rr) * H + k]) : 0.f;
        a[rr * H + k] = v;
    }
    __syncthreads();
    for (int cidx = threadIdx.x; cidx < VOCAB; cidx += 256) {
        const float4* wr = (const float4*)(Wo + (size_t)cidx * H);
        float acc[16];
        float bv = bo[cidx];
        #pragma unroll
        for (int rr = 0; rr < 16; ++rr) acc[rr] = bv;
        for (int k4 = 0; k4 < H / 4; ++k4) {
            float4 w = wr[k4];
            #pragma unroll
            for (int rr = 0; rr < 16; ++rr) {
                float4 av = a4[rr][k4];
                acc[rr] += av.x * w.x + av.y * w.y + av.z * w.z + av.w * w.w;
            }
        }
        for (int rr = 0; rr < nrow; ++rr) {
            int t = t0 + ct0 + rr;
            if (t >= STEPS) break;
            pred[((size_t)b * STEPS + t) * VOCAB + cidx] = (t < steps_b) ? acc[rr] : -1.f;
        }
    }
}

extern "C" void kernel_launch(void* const* d_in, const int* in_sizes, int n_in,
                              void* d_out, int out_size, void* d_ws, size_t ws_size,
                              hipStream_t stream) {
    const float* enc   = (const float*)d_in[0];
    const float* caps  = (const float*)d_in[1];
    const float* w_ih  = (const float*)d_in[2];
    const float* w_hh  = (const float*)d_in[3];
    const float* b_ih  = (const float*)d_in[4];
    const float* b_hh  = (const float*)d_in[5];
    const float* W_out = (const float*)d_in[6];
    const float* b_out = (const float*)d_in[7];
    const float* W_emb = (const float*)d_in[8];
    const float* b_emb = (const float*)d_in[9];
    const float* W_h   = (const float*)d_in[10];
    const float* b_h   = (const float*)d_in[11];
    const float* W_c   = (const float*)d_in[12];
    const float* b_c   = (const float*)d_in[13];
    const int*   lens  = (const int*)d_in[14];

    float* out_pred = (float*)d_out;
    float* out_caps = out_pred + (size_t)BS * STEPS * VOCAB;
    float* out_dec  = out_caps + (size_t)BS * T * WV;
    float* out_sidx = out_dec + BS;

    char* w = (char*)d_ws;
    size_t off = 0;
    auto take = [&](size_t bytes) -> char* {
        char* p = w + off;
        off += (bytes + 255) & ~(size_t)255;
        return p;
    };
    int*     sidx = (int*)take(BS * 4);
    int*     dlen = (int*)take(BS * 4);
    float*   Wc   = (float*)take((size_t)G4 * WV * 4);
    float*   bc   = (float*)take(G4 * 4);
    float*   h_st = (float*)take((size_t)BS * H * 4);
    float*   c_st = (float*)take((size_t)BS * H * 4);
    __half2* wT   = (__half2*)take((size_t)(H / 2) * G4 * 4);

    size_t rem = (ws_size > off) ? (ws_size - off) : 0;
    size_t per_step = (size_t)BS * G4 * 4 + (size_t)BS * H * 2 + 1024;
    int C = (int)(rem / per_step);
    if (C < 1) C = 1;
    if (C > STEPS) C = STEPS;
    float*  xg  = (float*)take((size_t)BS * C * G4 * 4);
    __half* hck = (__half*)take((size_t)BS * C * H * 2);

    // allow 138 KB dynamic LDS for the recurrent kernel (host-side, capture-safe)
    (void)hipFuncSetAttribute((const void*)k_lstm,
                              hipFuncAttributeMaxDynamicSharedMemorySize, LSTM_SMEM);

    k_sort<<<1, 256, 0, stream>>>(lens, sidx, dlen, out_dec, out_sidx);
    k_gather<<<BS, 256, 0, stream>>>(caps, sidx, out_caps);
    k_wcomb<<<G4 * WV / 256, 256, 0, stream>>>(w_ih, W_emb, Wc);
    k_bcomb<<<G4 / 256, 256, 0, stream>>>(w_ih, b_ih, b_hh, b_emb, bc);
    k_packw<<<(H / 2) * G4 / 256, 256, 0, stream>>>(w_hh, wT);
    k_inithc<<<BS, 256, 0, stream>>>(enc, sidx, W_h, b_h, W_c, b_c, h_st, c_st);

    for (int t0 = 0; t0 < STEPS; t0 += C) {
        int Cc = STEPS - t0; if (Cc > C) Cc = C;
        dim3 g((Cc + 15) / 16, BS);
        k_xg<<<g, 256, 0, stream>>>(out_caps, Wc, bc, dlen, xg, t0, Cc);
        k_lstm<<<BS, 512, LSTM_SMEM, stream>>>(wT, xg, dlen, h_st, c_st, hck, t0, Cc);
        k_logits<<<g, 256, 0, stream>>>(hck, W_out, b_out, dlen, out_pred, t0, Cc);
    }
}

// Round 6
// 1797.720 us; speedup vs baseline: 9.1011x; 1.1584x over previous
//
#include <hip/hip_runtime.h>
#include <hip/hip_fp16.h>

#define BS 256
#define T 256
#define STEPS 255
#define WV 100
#define INP 64
#define H 256
#define G4 1024
#define VOCAB 600

// ---------------- packed f16 dot2 with f32 accumulate ---------------------
typedef _Float16 f16x2 __attribute__((ext_vector_type(2)));

__device__ __forceinline__ float fdot2(unsigned w, unsigned h, float acc) {
#if defined(__has_builtin) && __has_builtin(__builtin_amdgcn_fdot2)
    return __builtin_amdgcn_fdot2(__builtin_bit_cast(f16x2, w),
                                  __builtin_bit_cast(f16x2, h), acc, false);
#else
    __half2 wv = *(const __half2*)&w;
    __half2 hv = *(const __half2*)&h;
    float2 wf = __half22float2(wv), hf = __half22float2(hv);
    return acc + wf.x * hf.x + wf.y * hf.y;
#endif
}

// quad (4-lane) sum via DPP quad_perm xor1 + xor2 — VALU pipe, no LDS.
__device__ __forceinline__ float quad_reduce(float x) {
    int a = __builtin_bit_cast(int, x);
    int b = __builtin_amdgcn_update_dpp(0, a, 0xB1, 0xF, 0xF, true);  // [1,0,3,2]
    float s = x + __builtin_bit_cast(float, b);
    int c = __builtin_bit_cast(int, s);
    int d = __builtin_amdgcn_update_dpp(0, c, 0x4E, 0xF, 0xF, true);  // [2,3,0,1]
    return s + __builtin_bit_cast(float, d);
}

// ---------------- sort: stable descending by length (jax argsort(-len)) ----
__global__ void k_sort(const int* __restrict__ lens, int* __restrict__ sidx,
                       int* __restrict__ dlen, float* __restrict__ out_dec,
                       float* __restrict__ out_sidx) {
    __shared__ int L[BS];
    int i = threadIdx.x;
    L[i] = lens[i];
    __syncthreads();
    int li = L[i];
    int r = 0;
    for (int j = 0; j < BS; ++j) {
        int lj = L[j];
        r += (lj > li) || (lj == li && j < i);
    }
    sidx[r] = i;
    dlen[r] = li - 1;
    out_sidx[r] = (float)i;
    out_dec[r]  = (float)(li - 1);
}

// ---------------- gather sorted captions to output ------------------------
__global__ void k_gather(const float* __restrict__ cin, const int* __restrict__ sidx,
                         float* __restrict__ cout) {
    int b = blockIdx.x;
    int src = sidx[b];
    const float4* in  = (const float4*)(cin + (size_t)src * T * WV);
    float4* out       = (float4*)(cout + (size_t)b * T * WV);
    for (int i = threadIdx.x; i < T * WV / 4; i += 256) out[i] = in[i];
}

// ---------------- W_comb = w_ih @ W_emb^T  [1024 x 100] -------------------
__global__ void k_wcomb(const float* __restrict__ w_ih, const float* __restrict__ W_emb,
                        float* __restrict__ Wc) {
    int idx = blockIdx.x * 256 + threadIdx.x;   // 102400 threads
    int r = idx / WV, cc = idx % WV;
    float acc = 0.f;
    for (int k = 0; k < INP; ++k) acc += w_ih[r * INP + k] * W_emb[k * WV + cc];
    Wc[idx] = acc;
}

// ---------------- b_comb = b_ih + b_hh + w_ih @ b_emb ---------------------
__global__ void k_bcomb(const float* __restrict__ w_ih, const float* __restrict__ b_ih,
                        const float* __restrict__ b_hh, const float* __restrict__ b_emb,
                        float* __restrict__ bc) {
    int r = blockIdx.x * 256 + threadIdx.x;     // 1024 threads
    float acc = b_ih[r] + b_hh[r];
    for (int k = 0; k < INP; ++k) acc += w_ih[r * INP + k] * b_emb[k];
    bc[r] = acc;
}

// ---------------- pack w_hh -> fp16, ROW-major half2 ----------------------
// wR[row*128 + k2] = half2(w_hh[row][2k2], w_hh[row][2k2+1])
__global__ void k_packw(const float* __restrict__ w_hh, __half2* __restrict__ wR) {
    int idx = blockIdx.x * 256 + threadIdx.x;   // 131072 threads
    wR[idx] = __floats2half2_rn(w_hh[(size_t)idx * 2], w_hh[(size_t)idx * 2 + 1]);
}

// ---------------- h0 = enc@W_h^T + b_h ; c0 = enc@W_c^T + b_c -------------
__global__ void k_inithc(const float* __restrict__ enc, const int* __restrict__ sidx,
                         const float* __restrict__ W_h, const float* __restrict__ b_h,
                         const float* __restrict__ W_c, const float* __restrict__ b_c,
                         float* __restrict__ h_st, float* __restrict__ c_st) {
    int b = blockIdx.x, j = threadIdx.x;
    __shared__ __align__(16) float e[INP];
    int src = sidx[b];
    if (j < INP) e[j] = enc[src * INP + j];
    __syncthreads();
    const float4* e4  = (const float4*)e;
    const float4* wh4 = (const float4*)(W_h + (size_t)j * INP);
    const float4* wc4 = (const float4*)(W_c + (size_t)j * INP);
    float ah = b_h[j], ac = b_c[j];
    #pragma unroll
    for (int k4 = 0; k4 < INP / 4; ++k4) {
        float4 ev = e4[k4];
        float4 wh = wh4[k4];
        float4 wc = wc4[k4];
        ah += ev.x * wh.x + ev.y * wh.y + ev.z * wh.z + ev.w * wh.w;
        ac += ev.x * wc.x + ev.y * wc.y + ev.z * wc.z + ev.w * wc.w;
    }
    h_st[b * H + j] = ah;
    c_st[b * H + j] = ac;
}

// ---------------- xg[b,ct,:] = caps_sorted[b,t,:] @ W_comb^T + b_comb -----
// 16-row tiles: acc[16] stays in registers (acc[32] spilled -> 20 GB scratch).
__global__ void k_xg(const float* __restrict__ caps, const float* __restrict__ Wc,
                     const float* __restrict__ bc, const int* __restrict__ dlen,
                     float* __restrict__ xg, int t0, int Cc) {
    int b = blockIdx.y;
    int ct0 = blockIdx.x * 16;
    if (t0 + ct0 >= dlen[b]) return;   // rows never consumed by the LSTM
    __shared__ __align__(16) float4 cs4[16][WV / 4];   // 16 timesteps x 100
    float* cs = (float*)cs4;
    for (int i = threadIdx.x; i < 16 * WV; i += 256) {
        int rr = i / WV, k = i % WV;
        int t = t0 + ct0 + rr;
        cs[rr * WV + k] = (t < T && ct0 + rr < Cc) ? caps[((size_t)b * T + t) * WV + k] : 0.f;
    }
    __syncthreads();
    int nrow = Cc - ct0; if (nrow > 16) nrow = 16;
    for (int rq = 0; rq < 4; ++rq) {
        int r = threadIdx.x + rq * 256;
        float acc[16];
        float bv = bc[r];
        #pragma unroll
        for (int rr = 0; rr < 16; ++rr) acc[rr] = bv;
        const float4* wr = (const float4*)(Wc + (size_t)r * WV);
        for (int k4 = 0; k4 < WV / 4; ++k4) {
            float4 w = wr[k4];
            #pragma unroll
            for (int rr = 0; rr < 16; ++rr) {
                float4 av = cs4[rr][k4];
                acc[rr] += av.x * w.x + av.y * w.y + av.z * w.z + av.w * w.w;
            }
        }
        for (int rr = 0; rr < nrow; ++rr)
            xg[((size_t)b * Cc + ct0 + rr) * G4 + r] = acc[rr];
    }
}

// ---------------- recurrent LSTM core: one block per batch row ------------
// K-SPLIT layout: quad (4 lanes) owns 8 gate-rows; lane q=lane&3 computes
// k-quarter [64q,64q+64) of all 8 rows. Rows j=0..5 weights in regs
// (wreg[6][8] uint4 = 192 dwords), rows j=6,7 from LDS (contiguous b128).
// h read per step: only MY quarter (8 hi + 8 lo uint4, each feeds 32 dots)
// -> 32 LDS insts/step vs 80 (broadcast b128 wastes 63/64 of returned BW).
// Quarter partials summed by 2 DPP quad-perm adds (VALU pipe, no LDS).
// Gate nonlinearity applied pre-barrier by distributed owners (wave-uniform
// gate id); epilogue = c/h update + 1 tanh only.
#define LSTM_SMEM (131072 + 4096 + 1152)   // wl 128K + gv 4K + padded h 1152B

__global__ __launch_bounds__(512)
__attribute__((amdgpu_waves_per_eu(2, 2)))
void k_lstm(const __half2* __restrict__ wR,
        const float* __restrict__ xg, const int* __restrict__ dlen,
        float* __restrict__ h_st, float* __restrict__ c_st,
        __half* __restrict__ hck, int t0, int Cc) {
    extern __shared__ __align__(16) char smem[];
    uint4*    wl4  = (uint4*)smem;                       // [u][s][Q][q] 8192 uint4
    float*    gv   = (float*)(smem + 131072);            // 1024 gate values
    unsigned* hpad = (unsigned*)(smem + 131072 + 4096);  // hi: 4 quarters x 36 dw
    unsigned* lpad = hpad + 144;                         // lo: same layout
    const uint4* hh4 = (const uint4*)hpad;               // quarter q chunk u: [q*9+u]
    const uint4* hl4 = (const uint4*)lpad;

    int b = blockIdx.x, tid = threadIdx.x;
    int steps_b = dlen[b];
    if (t0 >= steps_b) return;

    int lane = tid & 63;
    int q = lane & 3;                 // my k-quarter
    int Q = tid >> 2;                 // quad id 0..127, rows Q*8..Q*8+7
    int rowbase = Q * 8;
    int gate = __builtin_amdgcn_readfirstlane(tid >> 7);  // 0 i, 1 f, 2 g, 3 o

    const unsigned* wRu = (const unsigned*)wR;
    const uint4* wR4 = (const uint4*)wR;

    // ---- preload: rows j=0..5 -> regs; rows 6,7 -> LDS ----
    uint4 wreg[6][8];
    #pragma unroll
    for (int j = 0; j < 6; ++j)
        #pragma unroll
        for (int u = 0; u < 8; ++u)
            wreg[j][u] = wR4[(rowbase + j) * 32 + q * 8 + u];
    #pragma unroll
    for (int s = 0; s < 2; ++s)
        #pragma unroll
        for (int u = 0; u < 8; ++u)
            wl4[((u * 2 + s) * 128 + Q) * 4 + q] = wR4[(rowbase + 6 + s) * 32 + q * 8 + u];

    float c = 0.f, hcur = 0.f;
    if (tid < H) {
        hcur = h_st[b * H + tid];
        c    = c_st[b * H + tid];
        __half hh16 = __float2half(hcur);
        __half hl16 = __float2half(hcur - __half2float(hh16));
        int hidx = (tid >> 6) * 72 + (tid & 63);   // padded half-index
        ((__half*)hpad)[hidx] = hh16;
        ((__half*)lpad)[hidx] = hl16;
    }
    __syncthreads();

    int tend = t0 + Cc; if (tend > steps_b) tend = steps_b;
    const float* xgp = xg + (size_t)b * Cc * G4;
    __half* hckp = hck + (size_t)b * Cc * H;

    for (int t = t0; t < tend; ++t) {
        // xg for my 2 kept rows (issued early, consumed post-reduce)
        float x0 = xgp[rowbase + q];
        float x1 = xgp[rowbase + 4 + q];

        float ah[8], al[8];
        #pragma unroll
        for (int j = 0; j < 8; ++j) { ah[j] = 0.f; al[j] = 0.f; }

        #pragma unroll
        for (int u = 0; u < 8; ++u) {
            uint4 hh = hh4[q * 9 + u];
            uint4 hl = hl4[q * 9 + u];
            #pragma unroll
            for (int j = 0; j < 6; ++j) {
                uint4 w = wreg[j][u];
                ah[j] = fdot2(w.x, hh.x, ah[j]);
                ah[j] = fdot2(w.y, hh.y, ah[j]);
                ah[j] = fdot2(w.z, hh.z, ah[j]);
                ah[j] = fdot2(w.w, hh.w, ah[j]);
                al[j] = fdot2(w.x, hl.x, al[j]);
                al[j] = fdot2(w.y, hl.y, al[j]);
                al[j] = fdot2(w.z, hl.z, al[j]);
                al[j] = fdot2(w.w, hl.w, al[j]);
            }
            uint4 w6 = wl4[((u * 2 + 0) * 128 + Q) * 4 + q];
            uint4 w7 = wl4[((u * 2 + 1) * 128 + Q) * 4 + q];
            ah[6] = fdot2(w6.x, hh.x, ah[6]);
            ah[6] = fdot2(w6.y, hh.y, ah[6]);
            ah[6] = fdot2(w6.z, hh.z, ah[6]);
            ah[6] = fdot2(w6.w, hh.w, ah[6]);
            al[6] = fdot2(w6.x, hl.x, al[6]);
            al[6] = fdot2(w6.y, hl.y, al[6]);
            al[6] = fdot2(w6.z, hl.z, al[6]);
            al[6] = fdot2(w6.w, hl.w, al[6]);
            ah[7] = fdot2(w7.x, hh.x, ah[7]);
            ah[7] = fdot2(w7.y, hh.y, ah[7]);
            ah[7] = fdot2(w7.z, hh.z, ah[7]);
            ah[7] = fdot2(w7.w, hh.w, ah[7]);
            al[7] = fdot2(w7.x, hl.x, al[7]);
            al[7] = fdot2(w7.y, hl.y, al[7]);
            al[7] = fdot2(w7.z, hl.z, al[7]);
            al[7] = fdot2(w7.w, hl.w, al[7]);
        }

        // ---- quad reduction (DPP, no LDS) ----
        float tt[8];
        #pragma unroll
        for (int j = 0; j < 8; ++j) tt[j] = quad_reduce(ah[j] + al[j]);

        // lane keeps rows rowbase+q and rowbase+4+q (static cndmask select)
        float k0 = (q == 0) ? tt[0] : (q == 1) ? tt[1] : (q == 2) ? tt[2] : tt[3];
        float k1 = (q == 0) ? tt[4] : (q == 1) ? tt[5] : (q == 2) ? tt[6] : tt[7];
        float p0 = k0 + x0;
        float p1 = k1 + x1;
        if (gate == 2) { p0 = tanhf(p0); p1 = tanhf(p1); }
        else {
            p0 = 1.f / (1.f + __expf(-p0));
            p1 = 1.f / (1.f + __expf(-p1));
        }
        gv[rowbase + q]     = p0;
        gv[rowbase + 4 + q] = p1;
        __syncthreads();

        if (tid < H) {
            float iv  = gv[tid];
            float fv  = gv[256 + tid];
            float gvt = gv[512 + tid];
            float ov  = gv[768 + tid];
            c = fv * c + iv * gvt;
            float nh = ov * tanhf(c);
            hcur = nh;
            __half hh16 = __float2half(nh);
            __half hl16 = __float2half(nh - __half2float(hh16));
            hckp[tid] = hh16;
            int hidx = (tid >> 6) * 72 + (tid & 63);
            ((__half*)hpad)[hidx] = hh16;
            ((__half*)lpad)[hidx] = hl16;
        }
        __syncthreads();
        xgp += G4;
        hckp += H;
    }
    if (tid < H) { h_st[b * H + tid] = hcur; c_st[b * H + tid] = c; }
}

// ---------------- logits = h @ W_out^T + b_out, masked with -1 ------------
// 16-row tiles: acc[16] stays in registers (32-row variant spilled).
__global__ void k_logits(const __half* __restrict__ hck, const float* __restrict__ Wo,
                         const float* __restrict__ bo, const int* __restrict__ dlen,
                         float* __restrict__ pred, int t0, int Cc) {
    int b = blockIdx.y;
    int ct0 = blockIdx.x * 16;
    if (ct0 >= Cc) return;
    int steps_b = dlen[b];
    int nrow = Cc - ct0; if (nrow > 16) nrow = 16;
    if (t0 + ct0 >= steps_b) {   // whole tile inactive: write -1
        for (int rr = 0; rr < nrow; ++rr) {
            int t = t0 + ct0 + rr;
            if (t >= STEPS) break;
            float* pr = pred + ((size_t)b * STEPS + t) * VOCAB;
            for (int cidx = threadIdx.x; cidx < VOCAB; cidx += 256) pr[cidx] = -1.f;
        }
        return;
    }
    __shared__ __align__(16) float4 a4[16][H / 4];
    float* a = (float*)a4;
    for (int i = threadIdx.x; i < 16 * H; i += 256) {
        int rr = i >> 8, k = i & 255;
        float v = (rr < nrow) ? __half2float(hck[((size_t)b * Cc + ct0 + rr) * H + k]) : 0.f;
        a[rr * H + k] = v;
    }
    __syncthreads();
    for (int cidx = threadIdx.x; cidx < VOCAB; cidx += 256) {
        const float4* wr = (const float4*)(Wo + (size_t)cidx * H);
        float acc[16];
        float bv = bo[cidx];
        #pragma unroll
        for (int rr = 0; rr < 16; ++rr) acc[rr] = bv;
        for (int k4 = 0; k4 < H / 4; ++k4) {
            float4 w = wr[k4];
            #pragma unroll
            for (int rr = 0; rr < 16; ++rr) {
                float4 av = a4[rr][k4];
                acc[rr] += av.x * w.x + av.y * w.y + av.z * w.z + av.w * w.w;
            }
        }
        for (int rr = 0; rr < nrow; ++rr) {
            int t = t0 + ct0 + rr;
            if (t >= STEPS) break;
            pred[((size_t)b * STEPS + t) * VOCAB + cidx] = (t < steps_b) ? acc[rr] : -1.f;
        }
    }
}

extern "C" void kernel_launch(void* const* d_in, const int* in_sizes, int n_in,
                              void* d_out, int out_size, void* d_ws, size_t ws_size,
                              hipStream_t stream) {
    const float* enc   = (const float*)d_in[0];
    const float* caps  = (const float*)d_in[1];
    const float* w_ih  = (const float*)d_in[2];
    const float* w_hh  = (const float*)d_in[3];
    const float* b_ih  = (const float*)d_in[4];
    const float* b_hh  = (const float*)d_in[5];
    const float* W_out = (const float*)d_in[6];
    const float* b_out = (const float*)d_in[7];
    const float* W_emb = (const float*)d_in[8];
    const float* b_emb = (const float*)d_in[9];
    const float* W_h   = (const float*)d_in[10];
    const float* b_h   = (const float*)d_in[11];
    const float* W_c   = (const float*)d_in[12];
    const float* b_c   = (const float*)d_in[13];
    const int*   lens  = (const int*)d_in[14];

    float* out_pred = (float*)d_out;
    float* out_caps = out_pred + (size_t)BS * STEPS * VOCAB;
    float* out_dec  = out_caps + (size_t)BS * T * WV;
    float* out_sidx = out_dec + BS;

    char* w = (char*)d_ws;
    size_t off = 0;
    auto take = [&](size_t bytes) -> char* {
        char* p = w + off;
        off += (bytes + 255) & ~(size_t)255;
        return p;
    };
    int*     sidx = (int*)take(BS * 4);
    int*     dlen = (int*)take(BS * 4);
    float*   Wc   = (float*)take((size_t)G4 * WV * 4);
    float*   bc   = (float*)take(G4 * 4);
    float*   h_st = (float*)take((size_t)BS * H * 4);
    float*   c_st = (float*)take((size_t)BS * H * 4);
    __half2* wR   = (__half2*)take((size_t)G4 * (H / 2) * 4);

    size_t rem = (ws_size > off) ? (ws_size - off) : 0;
    size_t per_step = (size_t)BS * G4 * 4 + (size_t)BS * H * 2 + 1024;
    int C = (int)(rem / per_step);
    if (C < 1) C = 1;
    if (C > STEPS) C = STEPS;
    float*  xg  = (float*)take((size_t)BS * C * G4 * 4);
    __half* hck = (__half*)take((size_t)BS * C * H * 2);

    // allow 133 KB dynamic LDS for the recurrent kernel (host-side, capture-safe)
    (void)hipFuncSetAttribute((const void*)k_lstm,
                              hipFuncAttributeMaxDynamicSharedMemorySize, LSTM_SMEM);

    k_sort<<<1, 256, 0, stream>>>(lens, sidx, dlen, out_dec, out_sidx);
    k_gather<<<BS, 256, 0, stream>>>(caps, sidx, out_caps);
    k_wcomb<<<G4 * WV / 256, 256, 0, stream>>>(w_ih, W_emb, Wc);
    k_bcomb<<<G4 / 256, 256, 0, stream>>>(w_ih, b_ih, b_hh, b_emb, bc);
    k_packw<<<G4 * (H / 2) / 256, 256, 0, stream>>>(w_hh, wR);
    k_inithc<<<BS, 256, 0, stream>>>(enc, sidx, W_h, b_h, W_c, b_c, h_st, c_st);

    for (int t0 = 0; t0 < STEPS; t0 += C) {
        int Cc = STEPS - t0; if (Cc > C) Cc = C;
        dim3 g((Cc + 15) / 16, BS);
        k_xg<<<g, 256, 0, stream>>>(out_caps, Wc, bc, dlen, xg, t0, Cc);
        k_lstm<<<BS, 512, LSTM_SMEM, stream>>>(wR, xg, dlen, h_st, c_st, hck, t0, Cc);
        k_logits<<<g, 256, 0, stream>>>(hck, W_out, b_out, dlen, out_pred, t0, Cc);
    }
}

// Round 7
// 1503.993 us; speedup vs baseline: 10.8786x; 1.1953x over previous
//
#include <hip/hip_runtime.h>
#include <hip/hip_fp16.h>

#define BS 256
#define T 256
#define STEPS 255
#define WV 100
#define INP 64
#define H 256
#define G4 1024
#define VOCAB 600
#define VT 38            // vocab tiles of 16 (608, padded)

// ---------------- packed f16 dot2 with f32 accumulate ---------------------
typedef _Float16 f16x2 __attribute__((ext_vector_type(2)));
typedef _Float16 f16x8 __attribute__((ext_vector_type(8)));
typedef float f32x4 __attribute__((ext_vector_type(4)));

__device__ __forceinline__ float fdot2(unsigned w, unsigned h, float acc) {
#if defined(__has_builtin) && __has_builtin(__builtin_amdgcn_fdot2)
    return __builtin_amdgcn_fdot2(__builtin_bit_cast(f16x2, w),
                                  __builtin_bit_cast(f16x2, h), acc, false);
#else
    __half2 wv = *(const __half2*)&w;
    __half2 hv = *(const __half2*)&h;
    float2 wf = __half22float2(wv), hf = __half22float2(hv);
    return acc + wf.x * hf.x + wf.y * hf.y;
#endif
}

// quad (4-lane) sum via DPP quad_perm xor1 + xor2 — VALU pipe, no LDS.
__device__ __forceinline__ float quad_reduce(float x) {
    int a = __builtin_bit_cast(int, x);
    int b = __builtin_amdgcn_update_dpp(0, a, 0xB1, 0xF, 0xF, true);  // [1,0,3,2]
    float s = x + __builtin_bit_cast(float, b);
    int c = __builtin_bit_cast(int, s);
    int d = __builtin_amdgcn_update_dpp(0, c, 0x4E, 0xF, 0xF, true);  // [2,3,0,1]
    return s + __builtin_bit_cast(float, d);
}

__device__ __forceinline__ f32x4 mfma16(uint4 a, uint4 b, f32x4 c) {
    return __builtin_amdgcn_mfma_f32_16x16x32_f16(
        __builtin_bit_cast(f16x8, a), __builtin_bit_cast(f16x8, b), c, 0, 0, 0);
}

// ---------------- sort: stable descending by length (jax argsort(-len)) ----
__global__ void k_sort(const int* __restrict__ lens, int* __restrict__ sidx,
                       int* __restrict__ dlen, float* __restrict__ out_dec,
                       float* __restrict__ out_sidx) {
    __shared__ int L[BS];
    int i = threadIdx.x;
    L[i] = lens[i];
    __syncthreads();
    int li = L[i];
    int r = 0;
    for (int j = 0; j < BS; ++j) {
        int lj = L[j];
        r += (lj > li) || (lj == li && j < i);
    }
    sidx[r] = i;
    dlen[r] = li - 1;
    out_sidx[r] = (float)i;
    out_dec[r]  = (float)(li - 1);
}

// ---------------- gather sorted captions to output ------------------------
__global__ void k_gather(const float* __restrict__ cin, const int* __restrict__ sidx,
                         float* __restrict__ cout) {
    int b = blockIdx.x;
    int src = sidx[b];
    const float4* in  = (const float4*)(cin + (size_t)src * T * WV);
    float4* out       = (float4*)(cout + (size_t)b * T * WV);
    for (int i = threadIdx.x; i < T * WV / 4; i += 256) out[i] = in[i];
}

// ---------------- W_comb = w_ih @ W_emb^T  [1024 x 100] -------------------
__global__ void k_wcomb(const float* __restrict__ w_ih, const float* __restrict__ W_emb,
                        float* __restrict__ Wc) {
    int idx = blockIdx.x * 256 + threadIdx.x;   // 102400 threads
    int r = idx / WV, cc = idx % WV;
    float acc = 0.f;
    for (int k = 0; k < INP; ++k) acc += w_ih[r * INP + k] * W_emb[k * WV + cc];
    Wc[idx] = acc;
}

// ---------------- b_comb = b_ih + b_hh + w_ih @ b_emb ---------------------
__global__ void k_bcomb(const float* __restrict__ w_ih, const float* __restrict__ b_ih,
                        const float* __restrict__ b_hh, const float* __restrict__ b_emb,
                        float* __restrict__ bc) {
    int r = blockIdx.x * 256 + threadIdx.x;     // 1024 threads
    float acc = b_ih[r] + b_hh[r];
    for (int k = 0; k < INP; ++k) acc += w_ih[r * INP + k] * b_emb[k];
    bc[r] = acc;
}

// ---------------- pack w_hh -> fp16, ROW-major half2 ----------------------
// wR[row*128 + k2] = half2(w_hh[row][2k2], w_hh[row][2k2+1])
__global__ void k_packw(const float* __restrict__ w_hh, __half2* __restrict__ wR) {
    int idx = blockIdx.x * 256 + threadIdx.x;   // 131072 threads
    wR[idx] = __floats2half2_rn(w_hh[(size_t)idx * 2], w_hh[(size_t)idx * 2 + 1]);
}

// ---------------- pack W_out -> hi/lo f16 MFMA-B fragments ----------------
// Fragment order: element j of lane l for (vtile vt, ktile kt) holds
// Wo[v = vt*16 + (l&15)][k = kt*32 + (l>>4)*8 + j].  The SAME k-permutation
// is used for the A fragments, so the MFMA dot is exact under any HW wiring.
__global__ void k_packwo(const float* __restrict__ Wo, __half* __restrict__ woHi,
                         __half* __restrict__ woLo) {
    int idx = blockIdx.x * 256 + threadIdx.x;   // VT*8*64*8 = 155648 threads
    int fi = idx >> 9;           // vt*8 + kt
    int l  = (idx >> 3) & 63;
    int j  = idx & 7;
    int vt = fi >> 3, kt = fi & 7;
    int v = vt * 16 + (l & 15);
    int k = kt * 32 + ((l >> 4) << 3) + j;
    float w = (v < VOCAB) ? Wo[(size_t)v * H + k] : 0.f;
    __half hi = __float2half(w);
    __half lo = __float2half(w - __half2float(hi));
    woHi[idx] = hi;
    woLo[idx] = lo;
}

// ---------------- h0 = enc@W_h^T + b_h ; c0 = enc@W_c^T + b_c -------------
__global__ void k_inithc(const float* __restrict__ enc, const int* __restrict__ sidx,
                         const float* __restrict__ W_h, const float* __restrict__ b_h,
                         const float* __restrict__ W_c, const float* __restrict__ b_c,
                         float* __restrict__ h_st, float* __restrict__ c_st) {
    int b = blockIdx.x, j = threadIdx.x;
    __shared__ __align__(16) float e[INP];
    int src = sidx[b];
    if (j < INP) e[j] = enc[src * INP + j];
    __syncthreads();
    const float4* e4  = (const float4*)e;
    const float4* wh4 = (const float4*)(W_h + (size_t)j * INP);
    const float4* wc4 = (const float4*)(W_c + (size_t)j * INP);
    float ah = b_h[j], ac = b_c[j];
    #pragma unroll
    for (int k4 = 0; k4 < INP / 4; ++k4) {
        float4 ev = e4[k4];
        float4 wh = wh4[k4];
        float4 wc = wc4[k4];
        ah += ev.x * wh.x + ev.y * wh.y + ev.z * wh.z + ev.w * wh.w;
        ac += ev.x * wc.x + ev.y * wc.y + ev.z * wc.z + ev.w * wc.w;
    }
    h_st[b * H + j] = ah;
    c_st[b * H + j] = ac;
}

// ---------------- xg[b,ct,:] = caps_sorted[b,t,:] @ W_comb^T + b_comb -----
// 16-row tiles: acc[16] stays in registers (acc[32] spilled -> 20 GB scratch).
__global__ void k_xg(const float* __restrict__ caps, const float* __restrict__ Wc,
                     const float* __restrict__ bc, const int* __restrict__ dlen,
                     float* __restrict__ xg, int t0, int Cc) {
    int b = blockIdx.y;
    int ct0 = blockIdx.x * 16;
    if (t0 + ct0 >= dlen[b]) return;   // rows never consumed by the LSTM
    __shared__ __align__(16) float4 cs4[16][WV / 4];   // 16 timesteps x 100
    float* cs = (float*)cs4;
    for (int i = threadIdx.x; i < 16 * WV; i += 256) {
        int rr = i / WV, k = i % WV;
        int t = t0 + ct0 + rr;
        cs[rr * WV + k] = (t < T && ct0 + rr < Cc) ? caps[((size_t)b * T + t) * WV + k] : 0.f;
    }
    __syncthreads();
    int nrow = Cc - ct0; if (nrow > 16) nrow = 16;
    for (int rq = 0; rq < 4; ++rq) {
        int r = threadIdx.x + rq * 256;
        float acc[16];
        float bv = bc[r];
        #pragma unroll
        for (int rr = 0; rr < 16; ++rr) acc[rr] = bv;
        const float4* wr = (const float4*)(Wc + (size_t)r * WV);
        for (int k4 = 0; k4 < WV / 4; ++k4) {
            float4 w = wr[k4];
            #pragma unroll
            for (int rr = 0; rr < 16; ++rr) {
                float4 av = cs4[rr][k4];
                acc[rr] += av.x * w.x + av.y * w.y + av.z * w.z + av.w * w.w;
            }
        }
        for (int rr = 0; rr < nrow; ++rr)
            xg[((size_t)b * Cc + ct0 + rr) * G4 + r] = acc[rr];
    }
}

// ---------------- recurrent LSTM core (unchanged from round 6) ------------
#define LSTM_SMEM (131072 + 4096 + 1152)   // wl 128K + gv 4K + padded h 1152B

__global__ __launch_bounds__(512)
__attribute__((amdgpu_waves_per_eu(2, 2)))
void k_lstm(const __half2* __restrict__ wR,
        const float* __restrict__ xg, const int* __restrict__ dlen,
        float* __restrict__ h_st, float* __restrict__ c_st,
        __half* __restrict__ hck, int t0, int Cc) {
    extern __shared__ __align__(16) char smem[];
    uint4*    wl4  = (uint4*)smem;                       // [u][s][Q][q] 8192 uint4
    float*    gv   = (float*)(smem + 131072);            // 1024 gate values
    unsigned* hpad = (unsigned*)(smem + 131072 + 4096);  // hi: 4 quarters x 36 dw
    unsigned* lpad = hpad + 144;                         // lo: same layout
    const uint4* hh4 = (const uint4*)hpad;               // quarter q chunk u: [q*9+u]
    const uint4* hl4 = (const uint4*)lpad;

    int b = blockIdx.x, tid = threadIdx.x;
    int steps_b = dlen[b];
    if (t0 >= steps_b) return;

    int lane = tid & 63;
    int q = lane & 3;                 // my k-quarter
    int Q = tid >> 2;                 // quad id 0..127, rows Q*8..Q*8+7
    int rowbase = Q * 8;
    int gate = __builtin_amdgcn_readfirstlane(tid >> 7);  // 0 i, 1 f, 2 g, 3 o

    const uint4* wR4 = (const uint4*)wR;

    // ---- preload: rows j=0..5 -> regs; rows 6,7 -> LDS ----
    uint4 wreg[6][8];
    #pragma unroll
    for (int j = 0; j < 6; ++j)
        #pragma unroll
        for (int u = 0; u < 8; ++u)
            wreg[j][u] = wR4[(rowbase + j) * 32 + q * 8 + u];
    #pragma unroll
    for (int s = 0; s < 2; ++s)
        #pragma unroll
        for (int u = 0; u < 8; ++u)
            wl4[((u * 2 + s) * 128 + Q) * 4 + q] = wR4[(rowbase + 6 + s) * 32 + q * 8 + u];

    float c = 0.f, hcur = 0.f;
    if (tid < H) {
        hcur = h_st[b * H + tid];
        c    = c_st[b * H + tid];
        __half hh16 = __float2half(hcur);
        __half hl16 = __float2half(hcur - __half2float(hh16));
        int hidx = (tid >> 6) * 72 + (tid & 63);   // padded half-index
        ((__half*)hpad)[hidx] = hh16;
        ((__half*)lpad)[hidx] = hl16;
    }
    __syncthreads();

    int tend = t0 + Cc; if (tend > steps_b) tend = steps_b;
    const float* xgp = xg + (size_t)b * Cc * G4;
    __half* hckp = hck + (size_t)b * Cc * H;

    for (int t = t0; t < tend; ++t) {
        float x0 = xgp[rowbase + q];
        float x1 = xgp[rowbase + 4 + q];

        float ah[8], al[8];
        #pragma unroll
        for (int j = 0; j < 8; ++j) { ah[j] = 0.f; al[j] = 0.f; }

        #pragma unroll
        for (int u = 0; u < 8; ++u) {
            uint4 hh = hh4[q * 9 + u];
            uint4 hl = hl4[q * 9 + u];
            #pragma unroll
            for (int j = 0; j < 6; ++j) {
                uint4 w = wreg[j][u];
                ah[j] = fdot2(w.x, hh.x, ah[j]);
                ah[j] = fdot2(w.y, hh.y, ah[j]);
                ah[j] = fdot2(w.z, hh.z, ah[j]);
                ah[j] = fdot2(w.w, hh.w, ah[j]);
                al[j] = fdot2(w.x, hl.x, al[j]);
                al[j] = fdot2(w.y, hl.y, al[j]);
                al[j] = fdot2(w.z, hl.z, al[j]);
                al[j] = fdot2(w.w, hl.w, al[j]);
            }
            uint4 w6 = wl4[((u * 2 + 0) * 128 + Q) * 4 + q];
            uint4 w7 = wl4[((u * 2 + 1) * 128 + Q) * 4 + q];
            ah[6] = fdot2(w6.x, hh.x, ah[6]);
            ah[6] = fdot2(w6.y, hh.y, ah[6]);
            ah[6] = fdot2(w6.z, hh.z, ah[6]);
            ah[6] = fdot2(w6.w, hh.w, ah[6]);
            al[6] = fdot2(w6.x, hl.x, al[6]);
            al[6] = fdot2(w6.y, hl.y, al[6]);
            al[6] = fdot2(w6.z, hl.z, al[6]);
            al[6] = fdot2(w6.w, hl.w, al[6]);
            ah[7] = fdot2(w7.x, hh.x, ah[7]);
            ah[7] = fdot2(w7.y, hh.y, ah[7]);
            ah[7] = fdot2(w7.z, hh.z, ah[7]);
            ah[7] = fdot2(w7.w, hh.w, ah[7]);
            al[7] = fdot2(w7.x, hl.x, al[7]);
            al[7] = fdot2(w7.y, hl.y, al[7]);
            al[7] = fdot2(w7.z, hl.z, al[7]);
            al[7] = fdot2(w7.w, hl.w, al[7]);
        }

        // ---- quad reduction (DPP, no LDS) ----
        float tt[8];
        #pragma unroll
        for (int j = 0; j < 8; ++j) tt[j] = quad_reduce(ah[j] + al[j]);

        float k0 = (q == 0) ? tt[0] : (q == 1) ? tt[1] : (q == 2) ? tt[2] : tt[3];
        float k1 = (q == 0) ? tt[4] : (q == 1) ? tt[5] : (q == 2) ? tt[6] : tt[7];
        float p0 = k0 + x0;
        float p1 = k1 + x1;
        if (gate == 2) { p0 = tanhf(p0); p1 = tanhf(p1); }
        else {
            p0 = 1.f / (1.f + __expf(-p0));
            p1 = 1.f / (1.f + __expf(-p1));
        }
        gv[rowbase + q]     = p0;
        gv[rowbase + 4 + q] = p1;
        __syncthreads();

        if (tid < H) {
            float iv  = gv[tid];
            float fv  = gv[256 + tid];
            float gvt = gv[512 + tid];
            float ov  = gv[768 + tid];
            c = fv * c + iv * gvt;
            float nh = ov * tanhf(c);
            hcur = nh;
            __half hh16 = __float2half(nh);
            __half hl16 = __float2half(nh - __half2float(hh16));
            hckp[tid] = hh16;
            int hidx = (tid >> 6) * 72 + (tid & 63);
            ((__half*)hpad)[hidx] = hh16;
            ((__half*)lpad)[hidx] = hl16;
        }
        __syncthreads();
        xgp += G4;
        hckp += H;
    }
    if (tid < H) { h_st[b * H + tid] = hcur; c_st[b * H + tid] = c; }
}

// ---------------- logits via MFMA: pred = hck @ Wo^T + bo, masked ---------
// 1 wave per (32 timesteps x batch) tile; A = hck f16 (exact), B = Wo hi/lo
// f16 fragments (reconstructs f32 to ~1e-7).  A and B packed with the SAME
// k-permutation -> exact dot under any HW k-wiring; C/D mapping per m89:
// col = lane&15, row = (lane>>4)*4 + reg.
__global__ __launch_bounds__(64) void k_logits(const __half* __restrict__ hck,
        const __half* __restrict__ woHi, const __half* __restrict__ woLo,
        const float* __restrict__ bo, const int* __restrict__ dlen,
        float* __restrict__ pred, int t0, int Cc) {
    int b = blockIdx.y;
    int ct0 = blockIdx.x * 32;
    if (ct0 >= Cc) return;
    int steps_b = dlen[b];
    int l = threadIdx.x;
    int lhi = l >> 4, llo = l & 15;

    if (t0 + ct0 >= steps_b) {   // whole tile inactive: write -1
        for (int r = 0; r < 32; ++r) {
            int t = t0 + ct0 + r;
            if (r >= Cc - ct0 || t >= STEPS) break;
            float* pr = pred + ((size_t)b * STEPS + t) * VOCAB;
            for (int v = l; v < VOCAB; v += 64) pr[v] = -1.f;
        }
        return;
    }

    // A fragments: 2 M-tiles x 8 K-tiles; elem j = hck[row][kt*32 + lhi*8 + j]
    uint4 a[2][8];
    #pragma unroll
    for (int m = 0; m < 2; ++m) {
        int rr = ct0 + m * 16 + llo;
        int rc = (rr < Cc) ? rr : (Cc - 1);          // clamp (masked at store)
        const uint4* rp = (const uint4*)(hck + ((size_t)b * Cc + rc) * H);
        #pragma unroll
        for (int kt = 0; kt < 8; ++kt) a[m][kt] = rp[kt * 4 + lhi];
    }

    const uint4* bh4 = (const uint4*)woHi;
    const uint4* bl4 = (const uint4*)woLo;
    for (int vt = 0; vt < VT; ++vt) {
        int v = vt * 16 + llo;
        float bias = (v < VOCAB) ? bo[v] : 0.f;
        f32x4 acc0 = {bias, bias, bias, bias};
        f32x4 acc1 = acc0;
        #pragma unroll
        for (int kt = 0; kt < 8; ++kt) {
            uint4 bh = bh4[(vt * 8 + kt) * 64 + l];
            acc0 = mfma16(a[0][kt], bh, acc0);
            acc1 = mfma16(a[1][kt], bh, acc1);
        }
        #pragma unroll
        for (int kt = 0; kt < 8; ++kt) {
            uint4 bl = bl4[(vt * 8 + kt) * 64 + l];
            acc0 = mfma16(a[0][kt], bl, acc0);
            acc1 = mfma16(a[1][kt], bl, acc1);
        }
        if (v < VOCAB) {
            #pragma unroll
            for (int m = 0; m < 2; ++m) {
                f32x4 A = m ? acc1 : acc0;
                #pragma unroll
                for (int i = 0; i < 4; ++i) {
                    int r = ct0 + m * 16 + lhi * 4 + i;
                    int t = t0 + r;
                    if (r < Cc && t < STEPS)
                        pred[((size_t)b * STEPS + t) * VOCAB + v] =
                            (t < steps_b) ? A[i] : -1.f;
                }
            }
        }
    }
}

extern "C" void kernel_launch(void* const* d_in, const int* in_sizes, int n_in,
                              void* d_out, int out_size, void* d_ws, size_t ws_size,
                              hipStream_t stream) {
    const float* enc   = (const float*)d_in[0];
    const float* caps  = (const float*)d_in[1];
    const float* w_ih  = (const float*)d_in[2];
    const float* w_hh  = (const float*)d_in[3];
    const float* b_ih  = (const float*)d_in[4];
    const float* b_hh  = (const float*)d_in[5];
    const float* W_out = (const float*)d_in[6];
    const float* b_out = (const float*)d_in[7];
    const float* W_emb = (const float*)d_in[8];
    const float* b_emb = (const float*)d_in[9];
    const float* W_h   = (const float*)d_in[10];
    const float* b_h   = (const float*)d_in[11];
    const float* W_c   = (const float*)d_in[12];
    const float* b_c   = (const float*)d_in[13];
    const int*   lens  = (const int*)d_in[14];

    float* out_pred = (float*)d_out;
    float* out_caps = out_pred + (size_t)BS * STEPS * VOCAB;
    float* out_dec  = out_caps + (size_t)BS * T * WV;
    float* out_sidx = out_dec + BS;

    char* w = (char*)d_ws;
    size_t off = 0;
    auto take = [&](size_t bytes) -> char* {
        char* p = w + off;
        off += (bytes + 255) & ~(size_t)255;
        return p;
    };
    int*     sidx = (int*)take(BS * 4);
    int*     dlen = (int*)take(BS * 4);
    float*   Wc   = (float*)take((size_t)G4 * WV * 4);
    float*   bc   = (float*)take(G4 * 4);
    float*   h_st = (float*)take((size_t)BS * H * 4);
    float*   c_st = (float*)take((size_t)BS * H * 4);
    __half2* wR   = (__half2*)take((size_t)G4 * (H / 2) * 4);
    __half*  woHi = (__half*)take((size_t)VT * 8 * 64 * 8 * 2);
    __half*  woLo = (__half*)take((size_t)VT * 8 * 64 * 8 * 2);

    size_t rem = (ws_size > off) ? (ws_size - off) : 0;
    size_t per_step = (size_t)BS * G4 * 4 + (size_t)BS * H * 2 + 1024;
    int C = (int)(rem / per_step);
    if (C < 1) C = 1;
    if (C > STEPS) C = STEPS;
    float*  xg  = (float*)take((size_t)BS * C * G4 * 4);
    __half* hck = (__half*)take((size_t)BS * C * H * 2);

    // allow 133 KB dynamic LDS for the recurrent kernel (host-side, capture-safe)
    (void)hipFuncSetAttribute((const void*)k_lstm,
                              hipFuncAttributeMaxDynamicSharedMemorySize, LSTM_SMEM);

    k_sort<<<1, 256, 0, stream>>>(lens, sidx, dlen, out_dec, out_sidx);
    k_gather<<<BS, 256, 0, stream>>>(caps, sidx, out_caps);
    k_wcomb<<<G4 * WV / 256, 256, 0, stream>>>(w_ih, W_emb, Wc);
    k_bcomb<<<G4 / 256, 256, 0, stream>>>(w_ih, b_ih, b_hh, b_emb, bc);
    k_packw<<<G4 * (H / 2) / 256, 256, 0, stream>>>(w_hh, wR);
    k_packwo<<<VT * 8 * 64 * 8 / 256, 256, 0, stream>>>(W_out, woHi, woLo);
    k_inithc<<<BS, 256, 0, stream>>>(enc, sidx, W_h, b_h, W_c, b_c, h_st, c_st);

    for (int t0 = 0; t0 < STEPS; t0 += C) {
        int Cc = STEPS - t0; if (Cc > C) Cc = C;
        dim3 gx((Cc + 15) / 16, BS);
        dim3 gl((Cc + 31) / 32, BS);
        k_xg<<<gx, 256, 0, stream>>>(out_caps, Wc, bc, dlen, xg, t0, Cc);
        k_lstm<<<BS, 512, LSTM_SMEM, stream>>>(wR, xg, dlen, h_st, c_st, hck, t0, Cc);
        k_logits<<<gl, 64, 0, stream>>>(hck, woHi, woLo, b_out, dlen, out_pred, t0, Cc);
    }
}

// Round 8
// 1320.405 us; speedup vs baseline: 12.3911x; 1.1390x over previous
//
#include <hip/hip_runtime.h>
#include <hip/hip_fp16.h>

#define BS 256
#define T 256
#define STEPS 255
#define WV 100
#define INP 64
#define H 256
#define G4 1024
#define VOCAB 600
#define VT 38            // vocab tiles of 16 (608, padded)

// ---------------- packed f16 dot2 with f32 accumulate ---------------------
typedef _Float16 f16x2 __attribute__((ext_vector_type(2)));
typedef _Float16 f16x8 __attribute__((ext_vector_type(8)));
typedef float f32x4 __attribute__((ext_vector_type(4)));

__device__ __forceinline__ float fdot2(unsigned w, unsigned h, float acc) {
#if defined(__has_builtin) && __has_builtin(__builtin_amdgcn_fdot2)
    return __builtin_amdgcn_fdot2(__builtin_bit_cast(f16x2, w),
                                  __builtin_bit_cast(f16x2, h), acc, false);
#else
    __half2 wv = *(const __half2*)&w;
    __half2 hv = *(const __half2*)&h;
    float2 wf = __half22float2(wv), hf = __half22float2(hv);
    return acc + wf.x * hf.x + wf.y * hf.y;
#endif
}

// quad (4-lane) sum via DPP quad_perm xor1 + xor2 — VALU pipe, no LDS.
__device__ __forceinline__ float quad_reduce(float x) {
    int a = __builtin_bit_cast(int, x);
    int b = __builtin_amdgcn_update_dpp(0, a, 0xB1, 0xF, 0xF, true);  // [1,0,3,2]
    float s = x + __builtin_bit_cast(float, b);
    int c = __builtin_bit_cast(int, s);
    int d = __builtin_amdgcn_update_dpp(0, c, 0x4E, 0xF, 0xF, true);  // [2,3,0,1]
    return s + __builtin_bit_cast(float, d);
}

__device__ __forceinline__ f32x4 mfma16(uint4 a, uint4 b, f32x4 c) {
    return __builtin_amdgcn_mfma_f32_16x16x32_f16(
        __builtin_bit_cast(f16x8, a), __builtin_bit_cast(f16x8, b), c, 0, 0, 0);
}

// ---------------- sort: stable descending by length (jax argsort(-len)) ----
__global__ void k_sort(const int* __restrict__ lens, int* __restrict__ sidx,
                       int* __restrict__ dlen, float* __restrict__ out_dec,
                       float* __restrict__ out_sidx) {
    __shared__ int L[BS];
    int i = threadIdx.x;
    L[i] = lens[i];
    __syncthreads();
    int li = L[i];
    int r = 0;
    for (int j = 0; j < BS; ++j) {
        int lj = L[j];
        r += (lj > li) || (lj == li && j < i);
    }
    sidx[r] = i;
    dlen[r] = li - 1;
    out_sidx[r] = (float)i;
    out_dec[r]  = (float)(li - 1);
}

// ---------------- gather sorted captions to output ------------------------
__global__ void k_gather(const float* __restrict__ cin, const int* __restrict__ sidx,
                         float* __restrict__ cout) {
    int b = blockIdx.x;
    int src = sidx[b];
    const float4* in  = (const float4*)(cin + (size_t)src * T * WV);
    float4* out       = (float4*)(cout + (size_t)b * T * WV);
    for (int i = threadIdx.x; i < T * WV / 4; i += 256) out[i] = in[i];
}

// ---------------- W_comb = w_ih @ W_emb^T  [1024 x 100] -------------------
__global__ void k_wcomb(const float* __restrict__ w_ih, const float* __restrict__ W_emb,
                        float* __restrict__ Wc) {
    int idx = blockIdx.x * 256 + threadIdx.x;   // 102400 threads
    int r = idx / WV, cc = idx % WV;
    float acc = 0.f;
    for (int k = 0; k < INP; ++k) acc += w_ih[r * INP + k] * W_emb[k * WV + cc];
    Wc[idx] = acc;
}

// ---------------- b_comb = b_ih + b_hh + w_ih @ b_emb ---------------------
__global__ void k_bcomb(const float* __restrict__ w_ih, const float* __restrict__ b_ih,
                        const float* __restrict__ b_hh, const float* __restrict__ b_emb,
                        float* __restrict__ bc) {
    int r = blockIdx.x * 256 + threadIdx.x;     // 1024 threads
    float acc = b_ih[r] + b_hh[r];
    for (int k = 0; k < INP; ++k) acc += w_ih[r * INP + k] * b_emb[k];
    bc[r] = acc;
}

// ---------------- pack w_hh -> fp16, ROW-major half2 ----------------------
__global__ void k_packw(const float* __restrict__ w_hh, __half2* __restrict__ wR) {
    int idx = blockIdx.x * 256 + threadIdx.x;   // 131072 threads
    wR[idx] = __floats2half2_rn(w_hh[(size_t)idx * 2], w_hh[(size_t)idx * 2 + 1]);
}

// ---------------- pack W_out -> hi/lo f16 MFMA-B fragments ----------------
// elem j of lane l for (vt, kt): Wo[v = vt*16 + (l&15)][k = kt*32 + (l>>4)*8 + j]
__global__ void k_packwo(const float* __restrict__ Wo, __half* __restrict__ woHi,
                         __half* __restrict__ woLo) {
    int idx = blockIdx.x * 256 + threadIdx.x;   // VT*8*64*8 = 155648 threads
    int fi = idx >> 9;           // vt*8 + kt
    int l  = (idx >> 3) & 63;
    int j  = idx & 7;
    int vt = fi >> 3, kt = fi & 7;
    int v = vt * 16 + (l & 15);
    int k = kt * 32 + ((l >> 4) << 3) + j;
    float w = (v < VOCAB) ? Wo[(size_t)v * H + k] : 0.f;
    __half hi = __float2half(w);
    __half lo = __float2half(w - __half2float(hi));
    woHi[idx] = hi;
    woLo[idx] = lo;
}

// ---------------- pack sorted caps -> hi/lo f16 planes [b][t][128] --------
// K padded 100 -> 128 with zeros; A-fragments become direct uint4 loads.
__global__ void k_packcaps(const float* __restrict__ caps, __half* __restrict__ cHi,
                           __half* __restrict__ cLo) {
    int idx = blockIdx.x * 256 + threadIdx.x;    // BS*T*128 = 8.4M threads
    int k = idx & 127;
    int bt = idx >> 7;
    float v = (k < WV) ? caps[(size_t)bt * WV + k] : 0.f;
    __half hi = __float2half(v);
    cHi[idx] = hi;
    cLo[idx] = __float2half(v - __half2float(hi));
}

// ---------------- pack W_comb -> hi/lo f16 MFMA-B fragments ---------------
// elem j of lane l for (nt, kt): Wc[n = nt*16 + (l&15)][k = kt*32 + (l>>4)*8 + j]
__global__ void k_packwc(const float* __restrict__ Wc, __half* __restrict__ wcHi,
                         __half* __restrict__ wcLo) {
    int idx = blockIdx.x * 256 + threadIdx.x;   // 64*4*64*8 = 131072 threads
    int fi = idx >> 9;          // nt*4 + kt
    int l  = (idx >> 3) & 63;
    int j  = idx & 7;
    int nt = fi >> 2, kt = fi & 3;
    int n = nt * 16 + (l & 15);
    int k = kt * 32 + ((l >> 4) << 3) + j;
    float w = (k < WV) ? Wc[(size_t)n * WV + k] : 0.f;
    __half hi = __float2half(w);
    wcHi[idx] = hi;
    wcLo[idx] = __float2half(w - __half2float(hi));
}

// ---------------- h0 = enc@W_h^T + b_h ; c0 = enc@W_c^T + b_c -------------
__global__ void k_inithc(const float* __restrict__ enc, const int* __restrict__ sidx,
                         const float* __restrict__ W_h, const float* __restrict__ b_h,
                         const float* __restrict__ W_c, const float* __restrict__ b_c,
                         float* __restrict__ h_st, float* __restrict__ c_st) {
    int b = blockIdx.x, j = threadIdx.x;
    __shared__ __align__(16) float e[INP];
    int src = sidx[b];
    if (j < INP) e[j] = enc[src * INP + j];
    __syncthreads();
    const float4* e4  = (const float4*)e;
    const float4* wh4 = (const float4*)(W_h + (size_t)j * INP);
    const float4* wc4 = (const float4*)(W_c + (size_t)j * INP);
    float ah = b_h[j], ac = b_c[j];
    #pragma unroll
    for (int k4 = 0; k4 < INP / 4; ++k4) {
        float4 ev = e4[k4];
        float4 wh = wh4[k4];
        float4 wc = wc4[k4];
        ah += ev.x * wh.x + ev.y * wh.y + ev.z * wh.z + ev.w * wh.w;
        ac += ev.x * wc.x + ev.y * wc.y + ev.z * wc.z + ev.w * wc.w;
    }
    h_st[b * H + j] = ah;
    c_st[b * H + j] = ac;
}

// ---------------- xg via MFMA: xg = caps @ Wc^T + bc ----------------------
// Same proven pattern as k_logits: A = caps hi/lo f16 planes, B = Wc hi/lo
// fragments with the SAME k-permutation; 3 of 4 hi/lo products (lo*lo
// <= 2^-22 relative, below f32 accumulate noise). Bias in acc init.
// 256 threads = 4 waves; wave w owns N-tiles w*16..w*16+15.
__global__ __launch_bounds__(256) void k_xg(const __half* __restrict__ cHi,
        const __half* __restrict__ cLo, const __half* __restrict__ wcHi,
        const __half* __restrict__ wcLo, const float* __restrict__ bc,
        const int* __restrict__ dlen, float* __restrict__ xg, int t0, int Cc) {
    int b = blockIdx.y;
    int ct0 = blockIdx.x * 32;
    if (t0 + ct0 >= dlen[b]) return;   // rows never consumed by the LSTM
    int tid = threadIdx.x;
    int l = tid & 63, wid = tid >> 6;
    int lhi = l >> 4, llo = l & 15;

    uint4 aH[2][4], aL[2][4];
    #pragma unroll
    for (int m = 0; m < 2; ++m) {
        int rr = ct0 + m * 16 + llo;
        if (rr >= Cc) rr = Cc - 1;              // clamp (store-masked)
        size_t base = ((size_t)b * T + (t0 + rr)) * 128 + lhi * 8;
        #pragma unroll
        for (int kt = 0; kt < 4; ++kt) {
            aH[m][kt] = *(const uint4*)(cHi + base + kt * 32);
            aL[m][kt] = *(const uint4*)(cLo + base + kt * 32);
        }
    }
    const uint4* bh4 = (const uint4*)wcHi;
    const uint4* bl4 = (const uint4*)wcLo;
    for (int i = 0; i < 16; ++i) {
        int nt = wid * 16 + i;
        float bias = bc[nt * 16 + llo];
        f32x4 acc0 = {bias, bias, bias, bias};
        f32x4 acc1 = acc0;
        #pragma unroll
        for (int kt = 0; kt < 4; ++kt) {
            uint4 bh = bh4[(nt * 4 + kt) * 64 + l];
            uint4 bl = bl4[(nt * 4 + kt) * 64 + l];
            acc0 = mfma16(aH[0][kt], bh, acc0);
            acc1 = mfma16(aH[1][kt], bh, acc1);
            acc0 = mfma16(aH[0][kt], bl, acc0);
            acc1 = mfma16(aH[1][kt], bl, acc1);
            acc0 = mfma16(aL[0][kt], bh, acc0);
            acc1 = mfma16(aL[1][kt], bh, acc1);
        }
        #pragma unroll
        for (int m = 0; m < 2; ++m) {
            f32x4 A = m ? acc1 : acc0;
            #pragma unroll
            for (int ii = 0; ii < 4; ++ii) {
                int rr = ct0 + m * 16 + lhi * 4 + ii;
                if (rr < Cc)
                    xg[((size_t)b * Cc + rr) * G4 + nt * 16 + llo] = A[ii];
            }
        }
    }
}

// ---------------- recurrent LSTM core (unchanged from round 6) ------------
#define LSTM_SMEM (131072 + 4096 + 1152)   // wl 128K + gv 4K + padded h 1152B

__global__ __launch_bounds__(512)
__attribute__((amdgpu_waves_per_eu(2, 2)))
void k_lstm(const __half2* __restrict__ wR,
        const float* __restrict__ xg, const int* __restrict__ dlen,
        float* __restrict__ h_st, float* __restrict__ c_st,
        __half* __restrict__ hck, int t0, int Cc) {
    extern __shared__ __align__(16) char smem[];
    uint4*    wl4  = (uint4*)smem;                       // [u][s][Q][q] 8192 uint4
    float*    gv   = (float*)(smem + 131072);            // 1024 gate values
    unsigned* hpad = (unsigned*)(smem + 131072 + 4096);  // hi: 4 quarters x 36 dw
    unsigned* lpad = hpad + 144;                         // lo: same layout
    const uint4* hh4 = (const uint4*)hpad;               // quarter q chunk u: [q*9+u]
    const uint4* hl4 = (const uint4*)lpad;

    int b = blockIdx.x, tid = threadIdx.x;
    int steps_b = dlen[b];
    if (t0 >= steps_b) return;

    int lane = tid & 63;
    int q = lane & 3;                 // my k-quarter
    int Q = tid >> 2;                 // quad id 0..127, rows Q*8..Q*8+7
    int rowbase = Q * 8;
    int gate = __builtin_amdgcn_readfirstlane(tid >> 7);  // 0 i, 1 f, 2 g, 3 o

    const uint4* wR4 = (const uint4*)wR;

    // ---- preload: rows j=0..5 -> regs; rows 6,7 -> LDS ----
    uint4 wreg[6][8];
    #pragma unroll
    for (int j = 0; j < 6; ++j)
        #pragma unroll
        for (int u = 0; u < 8; ++u)
            wreg[j][u] = wR4[(rowbase + j) * 32 + q * 8 + u];
    #pragma unroll
    for (int s = 0; s < 2; ++s)
        #pragma unroll
        for (int u = 0; u < 8; ++u)
            wl4[((u * 2 + s) * 128 + Q) * 4 + q] = wR4[(rowbase + 6 + s) * 32 + q * 8 + u];

    float c = 0.f, hcur = 0.f;
    if (tid < H) {
        hcur = h_st[b * H + tid];
        c    = c_st[b * H + tid];
        __half hh16 = __float2half(hcur);
        __half hl16 = __float2half(hcur - __half2float(hh16));
        int hidx = (tid >> 6) * 72 + (tid & 63);   // padded half-index
        ((__half*)hpad)[hidx] = hh16;
        ((__half*)lpad)[hidx] = hl16;
    }
    __syncthreads();

    int tend = t0 + Cc; if (tend > steps_b) tend = steps_b;
    const float* xgp = xg + (size_t)b * Cc * G4;
    __half* hckp = hck + (size_t)b * Cc * H;

    for (int t = t0; t < tend; ++t) {
        float x0 = xgp[rowbase + q];
        float x1 = xgp[rowbase + 4 + q];

        float ah[8], al[8];
        #pragma unroll
        for (int j = 0; j < 8; ++j) { ah[j] = 0.f; al[j] = 0.f; }

        #pragma unroll
        for (int u = 0; u < 8; ++u) {
            uint4 hh = hh4[q * 9 + u];
            uint4 hl = hl4[q * 9 + u];
            #pragma unroll
            for (int j = 0; j < 6; ++j) {
                uint4 w = wreg[j][u];
                ah[j] = fdot2(w.x, hh.x, ah[j]);
                ah[j] = fdot2(w.y, hh.y, ah[j]);
                ah[j] = fdot2(w.z, hh.z, ah[j]);
                ah[j] = fdot2(w.w, hh.w, ah[j]);
                al[j] = fdot2(w.x, hl.x, al[j]);
                al[j] = fdot2(w.y, hl.y, al[j]);
                al[j] = fdot2(w.z, hl.z, al[j]);
                al[j] = fdot2(w.w, hl.w, al[j]);
            }
            uint4 w6 = wl4[((u * 2 + 0) * 128 + Q) * 4 + q];
            uint4 w7 = wl4[((u * 2 + 1) * 128 + Q) * 4 + q];
            ah[6] = fdot2(w6.x, hh.x, ah[6]);
            ah[6] = fdot2(w6.y, hh.y, ah[6]);
            ah[6] = fdot2(w6.z, hh.z, ah[6]);
            ah[6] = fdot2(w6.w, hh.w, ah[6]);
            al[6] = fdot2(w6.x, hl.x, al[6]);
            al[6] = fdot2(w6.y, hl.y, al[6]);
            al[6] = fdot2(w6.z, hl.z, al[6]);
            al[6] = fdot2(w6.w, hl.w, al[6]);
            ah[7] = fdot2(w7.x, hh.x, ah[7]);
            ah[7] = fdot2(w7.y, hh.y, ah[7]);
            ah[7] = fdot2(w7.z, hh.z, ah[7]);
            ah[7] = fdot2(w7.w, hh.w, ah[7]);
            al[7] = fdot2(w7.x, hl.x, al[7]);
            al[7] = fdot2(w7.y, hl.y, al[7]);
            al[7] = fdot2(w7.z, hl.z, al[7]);
            al[7] = fdot2(w7.w, hl.w, al[7]);
        }

        // ---- quad reduction (DPP, no LDS) ----
        float tt[8];
        #pragma unroll
        for (int j = 0; j < 8; ++j) tt[j] = quad_reduce(ah[j] + al[j]);

        float k0 = (q == 0) ? tt[0] : (q == 1) ? tt[1] : (q == 2) ? tt[2] : tt[3];
        float k1 = (q == 0) ? tt[4] : (q == 1) ? tt[5] : (q == 2) ? tt[6] : tt[7];
        float p0 = k0 + x0;
        float p1 = k1 + x1;
        if (gate == 2) { p0 = tanhf(p0); p1 = tanhf(p1); }
        else {
            p0 = 1.f / (1.f + __expf(-p0));
            p1 = 1.f / (1.f + __expf(-p1));
        }
        gv[rowbase + q]     = p0;
        gv[rowbase + 4 + q] = p1;
        __syncthreads();

        if (tid < H) {
            float iv  = gv[tid];
            float fv  = gv[256 + tid];
            float gvt = gv[512 + tid];
            float ov  = gv[768 + tid];
            c = fv * c + iv * gvt;
            float nh = ov * tanhf(c);
            hcur = nh;
            __half hh16 = __float2half(nh);
            __half hl16 = __float2half(nh - __half2float(hh16));
            hckp[tid] = hh16;
            int hidx = (tid >> 6) * 72 + (tid & 63);
            ((__half*)hpad)[hidx] = hh16;
            ((__half*)lpad)[hidx] = hl16;
        }
        __syncthreads();
        xgp += G4;
        hckp += H;
    }
    if (tid < H) { h_st[b * H + tid] = hcur; c_st[b * H + tid] = c; }
}

// ---------------- logits via MFMA (unchanged from round 7) ----------------
__global__ __launch_bounds__(64) void k_logits(const __half* __restrict__ hck,
        const __half* __restrict__ woHi, const __half* __restrict__ woLo,
        const float* __restrict__ bo, const int* __restrict__ dlen,
        float* __restrict__ pred, int t0, int Cc) {
    int b = blockIdx.y;
    int ct0 = blockIdx.x * 32;
    if (ct0 >= Cc) return;
    int steps_b = dlen[b];
    int l = threadIdx.x;
    int lhi = l >> 4, llo = l & 15;

    if (t0 + ct0 >= steps_b) {   // whole tile inactive: write -1
        for (int r = 0; r < 32; ++r) {
            int t = t0 + ct0 + r;
            if (r >= Cc - ct0 || t >= STEPS) break;
            float* pr = pred + ((size_t)b * STEPS + t) * VOCAB;
            for (int v = l; v < VOCAB; v += 64) pr[v] = -1.f;
        }
        return;
    }

    uint4 a[2][8];
    #pragma unroll
    for (int m = 0; m < 2; ++m) {
        int rr = ct0 + m * 16 + llo;
        int rc = (rr < Cc) ? rr : (Cc - 1);          // clamp (masked at store)
        const uint4* rp = (const uint4*)(hck + ((size_t)b * Cc + rc) * H);
        #pragma unroll
        for (int kt = 0; kt < 8; ++kt) a[m][kt] = rp[kt * 4 + lhi];
    }

    const uint4* bh4 = (const uint4*)woHi;
    const uint4* bl4 = (const uint4*)woLo;
    for (int vt = 0; vt < VT; ++vt) {
        int v = vt * 16 + llo;
        float bias = (v < VOCAB) ? bo[v] : 0.f;
        f32x4 acc0 = {bias, bias, bias, bias};
        f32x4 acc1 = acc0;
        #pragma unroll
        for (int kt = 0; kt < 8; ++kt) {
            uint4 bh = bh4[(vt * 8 + kt) * 64 + l];
            acc0 = mfma16(a[0][kt], bh, acc0);
            acc1 = mfma16(a[1][kt], bh, acc1);
        }
        #pragma unroll
        for (int kt = 0; kt < 8; ++kt) {
            uint4 bl = bl4[(vt * 8 + kt) * 64 + l];
            acc0 = mfma16(a[0][kt], bl, acc0);
            acc1 = mfma16(a[1][kt], bl, acc1);
        }
        if (v < VOCAB) {
            #pragma unroll
            for (int m = 0; m < 2; ++m) {
                f32x4 A = m ? acc1 : acc0;
                #pragma unroll
                for (int i = 0; i < 4; ++i) {
                    int r = ct0 + m * 16 + lhi * 4 + i;
                    int t = t0 + r;
                    if (r < Cc && t < STEPS)
                        pred[((size_t)b * STEPS + t) * VOCAB + v] =
                            (t < steps_b) ? A[i] : -1.f;
                }
            }
        }
    }
}

extern "C" void kernel_launch(void* const* d_in, const int* in_sizes, int n_in,
                              void* d_out, int out_size, void* d_ws, size_t ws_size,
                              hipStream_t stream) {
    const float* enc   = (const float*)d_in[0];
    const float* caps  = (const float*)d_in[1];
    const float* w_ih  = (const float*)d_in[2];
    const float* w_hh  = (const float*)d_in[3];
    const float* b_ih  = (const float*)d_in[4];
    const float* b_hh  = (const float*)d_in[5];
    const float* W_out = (const float*)d_in[6];
    const float* b_out = (const float*)d_in[7];
    const float* W_emb = (const float*)d_in[8];
    const float* b_emb = (const float*)d_in[9];
    const float* W_h   = (const float*)d_in[10];
    const float* b_h   = (const float*)d_in[11];
    const float* W_c   = (const float*)d_in[12];
    const float* b_c   = (const float*)d_in[13];
    const int*   lens  = (const int*)d_in[14];

    float* out_pred = (float*)d_out;
    float* out_caps = out_pred + (size_t)BS * STEPS * VOCAB;
    float* out_dec  = out_caps + (size_t)BS * T * WV;
    float* out_sidx = out_dec + BS;

    char* w = (char*)d_ws;
    size_t off = 0;
    auto take = [&](size_t bytes) -> char* {
        char* p = w + off;
        off += (bytes + 255) & ~(size_t)255;
        return p;
    };
    int*     sidx = (int*)take(BS * 4);
    int*     dlen = (int*)take(BS * 4);
    float*   Wc   = (float*)take((size_t)G4 * WV * 4);
    float*   bc   = (float*)take(G4 * 4);
    float*   h_st = (float*)take((size_t)BS * H * 4);
    float*   c_st = (float*)take((size_t)BS * H * 4);
    __half2* wR   = (__half2*)take((size_t)G4 * (H / 2) * 4);
    __half*  woHi = (__half*)take((size_t)VT * 8 * 64 * 8 * 2);
    __half*  woLo = (__half*)take((size_t)VT * 8 * 64 * 8 * 2);
    __half*  cHi  = (__half*)take((size_t)BS * T * 128 * 2);
    __half*  cLo  = (__half*)take((size_t)BS * T * 128 * 2);
    __half*  wcHi = (__half*)take((size_t)64 * 4 * 64 * 8 * 2);
    __half*  wcLo = (__half*)take((size_t)64 * 4 * 64 * 8 * 2);

    size_t rem = (ws_size > off) ? (ws_size - off) : 0;
    size_t per_step = (size_t)BS * G4 * 4 + (size_t)BS * H * 2 + 1024;
    int C = (int)(rem / per_step);
    if (C < 1) C = 1;
    if (C > STEPS) C = STEPS;
    float*  xg  = (float*)take((size_t)BS * C * G4 * 4);
    __half* hck = (__half*)take((size_t)BS * C * H * 2);

    // allow 133 KB dynamic LDS for the recurrent kernel (host-side, capture-safe)
    (void)hipFuncSetAttribute((const void*)k_lstm,
                              hipFuncAttributeMaxDynamicSharedMemorySize, LSTM_SMEM);

    k_sort<<<1, 256, 0, stream>>>(lens, sidx, dlen, out_dec, out_sidx);
    k_gather<<<BS, 256, 0, stream>>>(caps, sidx, out_caps);
    k_wcomb<<<G4 * WV / 256, 256, 0, stream>>>(w_ih, W_emb, Wc);
    k_bcomb<<<G4 / 256, 256, 0, stream>>>(w_ih, b_ih, b_hh, b_emb, bc);
    k_packw<<<G4 * (H / 2) / 256, 256, 0, stream>>>(w_hh, wR);
    k_packwo<<<VT * 8 * 64 * 8 / 256, 256, 0, stream>>>(W_out, woHi, woLo);
    k_packcaps<<<BS * T * 128 / 256, 256, 0, stream>>>(out_caps, cHi, cLo);
    k_packwc<<<64 * 4 * 64 * 8 / 256, 256, 0, stream>>>(Wc, wcHi, wcLo);
    k_inithc<<<BS, 256, 0, stream>>>(enc, sidx, W_h, b_h, W_c, b_c, h_st, c_st);

    for (int t0 = 0; t0 < STEPS; t0 += C) {
        int Cc = STEPS - t0; if (Cc > C) Cc = C;
        dim3 gx((Cc + 31) / 32, BS);
        k_xg<<<gx, 256, 0, stream>>>(cHi, cLo, wcHi, wcLo, bc, dlen, xg, t0, Cc);
        k_lstm<<<BS, 512, LSTM_SMEM, stream>>>(wR, xg, dlen, h_st, c_st, hck, t0, Cc);
        k_logits<<<gx, 64, 0, stream>>>(hck, woHi, woLo, b_out, dlen, out_pred, t0, Cc);
    }
}

// Round 9
// 1283.861 us; speedup vs baseline: 12.7438x; 1.0285x over previous
//
#include <hip/hip_runtime.h>
#include <hip/hip_fp16.h>

#define BS 256
#define T 256
#define STEPS 255
#define WV 100
#define INP 64
#define H 256
#define G4 1024
#define VOCAB 600
#define VT 38            // vocab tiles of 16 (608, padded)

// ---------------- packed f16 dot2 with f32 accumulate ---------------------
typedef _Float16 f16x2 __attribute__((ext_vector_type(2)));
typedef _Float16 f16x8 __attribute__((ext_vector_type(8)));
typedef float f32x4 __attribute__((ext_vector_type(4)));

__device__ __forceinline__ float fdot2(unsigned w, unsigned h, float acc) {
#if defined(__has_builtin) && __has_builtin(__builtin_amdgcn_fdot2)
    return __builtin_amdgcn_fdot2(__builtin_bit_cast(f16x2, w),
                                  __builtin_bit_cast(f16x2, h), acc, false);
#else
    __half2 wv = *(const __half2*)&w;
    __half2 hv = *(const __half2*)&h;
    float2 wf = __half22float2(wv), hf = __half22float2(hv);
    return acc + wf.x * hf.x + wf.y * hf.y;
#endif
}

// quad (4-lane) sum via DPP quad_perm xor1 + xor2 — VALU pipe, no LDS.
// Butterfly: every lane ends with the bitwise-identical total.
__device__ __forceinline__ float quad_reduce(float x) {
    int a = __builtin_bit_cast(int, x);
    int b = __builtin_amdgcn_update_dpp(0, a, 0xB1, 0xF, 0xF, true);  // [1,0,3,2]
    float s = x + __builtin_bit_cast(float, b);
    int c = __builtin_bit_cast(int, s);
    int d = __builtin_amdgcn_update_dpp(0, c, 0x4E, 0xF, 0xF, true);  // [2,3,0,1]
    return s + __builtin_bit_cast(float, d);
}

__device__ __forceinline__ f32x4 mfma16(uint4 a, uint4 b, f32x4 c) {
    return __builtin_amdgcn_mfma_f32_16x16x32_f16(
        __builtin_bit_cast(f16x8, a), __builtin_bit_cast(f16x8, b), c, 0, 0, 0);
}

// ---------------- sort: stable descending by length (jax argsort(-len)) ----
__global__ void k_sort(const int* __restrict__ lens, int* __restrict__ sidx,
                       int* __restrict__ dlen, float* __restrict__ out_dec,
                       float* __restrict__ out_sidx) {
    __shared__ int L[BS];
    int i = threadIdx.x;
    L[i] = lens[i];
    __syncthreads();
    int li = L[i];
    int r = 0;
    for (int j = 0; j < BS; ++j) {
        int lj = L[j];
        r += (lj > li) || (lj == li && j < i);
    }
    sidx[r] = i;
    dlen[r] = li - 1;
    out_sidx[r] = (float)i;
    out_dec[r]  = (float)(li - 1);
}

// ---------------- gather sorted captions to output ------------------------
__global__ void k_gather(const float* __restrict__ cin, const int* __restrict__ sidx,
                         float* __restrict__ cout) {
    int b = blockIdx.x;
    int src = sidx[b];
    const float4* in  = (const float4*)(cin + (size_t)src * T * WV);
    float4* out       = (float4*)(cout + (size_t)b * T * WV);
    for (int i = threadIdx.x; i < T * WV / 4; i += 256) out[i] = in[i];
}

// ---------------- W_comb = w_ih @ W_emb^T  [1024 x 100] -------------------
__global__ void k_wcomb(const float* __restrict__ w_ih, const float* __restrict__ W_emb,
                        float* __restrict__ Wc) {
    int idx = blockIdx.x * 256 + threadIdx.x;   // 102400 threads
    int r = idx / WV, cc = idx % WV;
    float acc = 0.f;
    for (int k = 0; k < INP; ++k) acc += w_ih[r * INP + k] * W_emb[k * WV + cc];
    Wc[idx] = acc;
}

// ---------------- b_comb = b_ih + b_hh + w_ih @ b_emb ---------------------
__global__ void k_bcomb(const float* __restrict__ w_ih, const float* __restrict__ b_ih,
                        const float* __restrict__ b_hh, const float* __restrict__ b_emb,
                        float* __restrict__ bc) {
    int r = blockIdx.x * 256 + threadIdx.x;     // 1024 threads
    float acc = b_ih[r] + b_hh[r];
    for (int k = 0; k < INP; ++k) acc += w_ih[r * INP + k] * b_emb[k];
    bc[r] = acc;
}

// ---------------- pack w_hh -> fp16, ROW-major half2 ----------------------
__global__ void k_packw(const float* __restrict__ w_hh, __half2* __restrict__ wR) {
    int idx = blockIdx.x * 256 + threadIdx.x;   // 131072 threads
    wR[idx] = __floats2half2_rn(w_hh[(size_t)idx * 2], w_hh[(size_t)idx * 2 + 1]);
}

// ---------------- pack W_out -> hi/lo f16 MFMA-B fragments ----------------
__global__ void k_packwo(const float* __restrict__ Wo, __half* __restrict__ woHi,
                         __half* __restrict__ woLo) {
    int idx = blockIdx.x * 256 + threadIdx.x;   // VT*8*64*8 = 155648 threads
    int fi = idx >> 9;           // vt*8 + kt
    int l  = (idx >> 3) & 63;
    int j  = idx & 7;
    int vt = fi >> 3, kt = fi & 7;
    int v = vt * 16 + (l & 15);
    int k = kt * 32 + ((l >> 4) << 3) + j;
    float w = (v < VOCAB) ? Wo[(size_t)v * H + k] : 0.f;
    __half hi = __float2half(w);
    __half lo = __float2half(w - __half2float(hi));
    woHi[idx] = hi;
    woLo[idx] = lo;
}

// ---------------- pack sorted caps -> hi/lo f16 planes [b][t][128] --------
__global__ void k_packcaps(const float* __restrict__ caps, __half* __restrict__ cHi,
                           __half* __restrict__ cLo) {
    int idx = blockIdx.x * 256 + threadIdx.x;    // BS*T*128 = 8.4M threads
    int k = idx & 127;
    int bt = idx >> 7;
    float v = (k < WV) ? caps[(size_t)bt * WV + k] : 0.f;
    __half hi = __float2half(v);
    cHi[idx] = hi;
    cLo[idx] = __float2half(v - __half2float(hi));
}

// ---------------- pack W_comb -> hi/lo f16 MFMA-B fragments ---------------
__global__ void k_packwc(const float* __restrict__ Wc, __half* __restrict__ wcHi,
                         __half* __restrict__ wcLo) {
    int idx = blockIdx.x * 256 + threadIdx.x;   // 64*4*64*8 = 131072 threads
    int fi = idx >> 9;          // nt*4 + kt
    int l  = (idx >> 3) & 63;
    int j  = idx & 7;
    int nt = fi >> 2, kt = fi & 3;
    int n = nt * 16 + (l & 15);
    int k = kt * 32 + ((l >> 4) << 3) + j;
    float w = (k < WV) ? Wc[(size_t)n * WV + k] : 0.f;
    __half hi = __float2half(w);
    wcHi[idx] = hi;
    wcLo[idx] = __float2half(w - __half2float(hi));
}

// ---------------- h0 = enc@W_h^T + b_h ; c0 = enc@W_c^T + b_c -------------
__global__ void k_inithc(const float* __restrict__ enc, const int* __restrict__ sidx,
                         const float* __restrict__ W_h, const float* __restrict__ b_h,
                         const float* __restrict__ W_c, const float* __restrict__ b_c,
                         float* __restrict__ h_st, float* __restrict__ c_st) {
    int b = blockIdx.x, j = threadIdx.x;
    __shared__ __align__(16) float e[INP];
    int src = sidx[b];
    if (j < INP) e[j] = enc[src * INP + j];
    __syncthreads();
    const float4* e4  = (const float4*)e;
    const float4* wh4 = (const float4*)(W_h + (size_t)j * INP);
    const float4* wc4 = (const float4*)(W_c + (size_t)j * INP);
    float ah = b_h[j], ac = b_c[j];
    #pragma unroll
    for (int k4 = 0; k4 < INP / 4; ++k4) {
        float4 ev = e4[k4];
        float4 wh = wh4[k4];
        float4 wc = wc4[k4];
        ah += ev.x * wh.x + ev.y * wh.y + ev.z * wh.z + ev.w * wh.w;
        ac += ev.x * wc.x + ev.y * wc.y + ev.z * wc.z + ev.w * wc.w;
    }
    h_st[b * H + j] = ah;
    c_st[b * H + j] = ac;
}

// ---------------- xg via MFMA (unchanged from round 8) --------------------
__global__ __launch_bounds__(256) void k_xg(const __half* __restrict__ cHi,
        const __half* __restrict__ cLo, const __half* __restrict__ wcHi,
        const __half* __restrict__ wcLo, const float* __restrict__ bc,
        const int* __restrict__ dlen, float* __restrict__ xg, int t0, int Cc) {
    int b = blockIdx.y;
    int ct0 = blockIdx.x * 32;
    if (t0 + ct0 >= dlen[b]) return;   // rows never consumed by the LSTM
    int tid = threadIdx.x;
    int l = tid & 63, wid = tid >> 6;
    int lhi = l >> 4, llo = l & 15;

    uint4 aH[2][4], aL[2][4];
    #pragma unroll
    for (int m = 0; m < 2; ++m) {
        int rr = ct0 + m * 16 + llo;
        if (rr >= Cc) rr = Cc - 1;              // clamp (store-masked)
        size_t base = ((size_t)b * T + (t0 + rr)) * 128 + lhi * 8;
        #pragma unroll
        for (int kt = 0; kt < 4; ++kt) {
            aH[m][kt] = *(const uint4*)(cHi + base + kt * 32);
            aL[m][kt] = *(const uint4*)(cLo + base + kt * 32);
        }
    }
    const uint4* bh4 = (const uint4*)wcHi;
    const uint4* bl4 = (const uint4*)wcLo;
    for (int i = 0; i < 16; ++i) {
        int nt = wid * 16 + i;
        float bias = bc[nt * 16 + llo];
        f32x4 acc0 = {bias, bias, bias, bias};
        f32x4 acc1 = acc0;
        #pragma unroll
        for (int kt = 0; kt < 4; ++kt) {
            uint4 bh = bh4[(nt * 4 + kt) * 64 + l];
            uint4 bl = bl4[(nt * 4 + kt) * 64 + l];
            acc0 = mfma16(aH[0][kt], bh, acc0);
            acc1 = mfma16(aH[1][kt], bh, acc1);
            acc0 = mfma16(aH[0][kt], bl, acc0);
            acc1 = mfma16(aH[1][kt], bl, acc1);
            acc0 = mfma16(aL[0][kt], bh, acc0);
            acc1 = mfma16(aL[1][kt], bh, acc1);
        }
        #pragma unroll
        for (int m = 0; m < 2; ++m) {
            f32x4 A = m ? acc1 : acc0;
            #pragma unroll
            for (int ii = 0; ii < 4; ++ii) {
                int rr = ct0 + m * 16 + lhi * 4 + ii;
                if (rr < Cc)
                    xg[((size_t)b * Cc + rr) * G4 + nt * 16 + llo] = A[ii];
            }
        }
    }
}

// ---------------- recurrent LSTM core: one block per batch row ------------
// ROUND 9: quad Q owns rows {i,f,g,o} x {2Q, 2Q+1} (8 gate-rows, k-quarter
// split as before).  After the DPP quad-reduce every lane holds ALL 8 gate
// pre-activations (butterfly = bitwise-equal on all lanes), so the complete
// cell update for rows 2Q,2Q+1 is quad-local: no gv exchange, no cross-wave
// epilogue, no idle half-block.  All lanes compute redundantly (zero
// divergence); lanes q<2 store.  h is DOUBLE-BUFFERED in LDS -> ONE barrier
// per step (was 2).  Dot math & reduce order identical to round 6 ->
// bitwise-same output.
#define LSTM_SMEM (131072 + 2 * 1152)   // wl 128K + h dbuf 2 x (hi144+lo144 dw)

__global__ __launch_bounds__(512)
__attribute__((amdgpu_waves_per_eu(2, 2)))
void k_lstm(const __half2* __restrict__ wR,
        const float* __restrict__ xg, const int* __restrict__ dlen,
        float* __restrict__ h_st, float* __restrict__ c_st,
        __half* __restrict__ hck, int t0, int Cc) {
    extern __shared__ __align__(16) char smem[];
    uint4*    wl4  = (uint4*)smem;                     // [u][s][Q][q] 8192 uint4
    unsigned* hbuf = (unsigned*)(smem + 131072);       // 2 bufs x (hi 144 + lo 144) dw

    int b = blockIdx.x, tid = threadIdx.x;
    int steps_b = dlen[b];
    if (t0 >= steps_b) return;

    int lane = tid & 63;
    int q = lane & 3;                 // my k-quarter
    int Q = tid >> 2;                 // quad id 0..127, h-rows 2Q, 2Q+1
    int rx = 2 * Q + (q & 1);         // the h-row this lane redundantly owns

    const uint4* wR4 = (const uint4*)wR;

    // gate-row table for this quad: j= {i r0, i r1, f r0, f r1, g r0, g r1}
    // in regs; {o r0, o r1} in LDS.
    uint4 wreg[6][8];
    #pragma unroll
    for (int j = 0; j < 6; ++j) {
        int grow = (j >> 1) * 256 + 2 * Q + (j & 1);   // gates i,f,g
        #pragma unroll
        for (int u = 0; u < 8; ++u)
            wreg[j][u] = wR4[grow * 32 + q * 8 + u];
    }
    #pragma unroll
    for (int s = 0; s < 2; ++s)
        #pragma unroll
        for (int u = 0; u < 8; ++u)
            wl4[((u * 2 + s) * 128 + Q) * 4 + q] =
                wR4[(768 + 2 * Q + s) * 32 + q * 8 + u];

    // init: every lane loads its row's h/c (dup addresses coalesce); q<2 store
    float c = c_st[b * H + rx];
    float hcur = h_st[b * H + rx];
    {
        __half hh16 = __float2half(hcur);
        __half hl16 = __float2half(hcur - __half2float(hh16));
        if (q < 2) {
            int hidx = (rx >> 6) * 72 + (rx & 63);
            ((__half*)(hbuf))[hidx] = hh16;           // buf 0 hi
            ((__half*)(hbuf + 144))[hidx] = hl16;     // buf 0 lo
        }
    }
    __syncthreads();

    int tend = t0 + Cc; if (tend > steps_b) tend = steps_b;
    const float* xgp = xg + (size_t)b * Cc * G4;
    __half* hckp = hck + (size_t)b * Cc * H;
    int p = 0;

    for (int t = t0; t < tend; ++t) {
        // xg for my row's 4 gates (dup loads across q-pairs coalesce)
        float xi = xgp[rx];
        float xf = xgp[256 + rx];
        float xgg = xgp[512 + rx];
        float xo = xgp[768 + rx];

        const uint4* hh4 = (const uint4*)(hbuf + p * 288);
        const uint4* hl4 = (const uint4*)(hbuf + p * 288 + 144);

        float ah[8], al[8];
        #pragma unroll
        for (int j = 0; j < 8; ++j) { ah[j] = 0.f; al[j] = 0.f; }

        #pragma unroll
        for (int u = 0; u < 8; ++u) {
            uint4 hh = hh4[q * 9 + u];
            uint4 hl = hl4[q * 9 + u];
            #pragma unroll
            for (int j = 0; j < 6; ++j) {
                uint4 w = wreg[j][u];
                ah[j] = fdot2(w.x, hh.x, ah[j]);
                ah[j] = fdot2(w.y, hh.y, ah[j]);
                ah[j] = fdot2(w.z, hh.z, ah[j]);
                ah[j] = fdot2(w.w, hh.w, ah[j]);
                al[j] = fdot2(w.x, hl.x, al[j]);
                al[j] = fdot2(w.y, hl.y, al[j]);
                al[j] = fdot2(w.z, hl.z, al[j]);
                al[j] = fdot2(w.w, hl.w, al[j]);
            }
            uint4 w6 = wl4[((u * 2 + 0) * 128 + Q) * 4 + q];
            uint4 w7 = wl4[((u * 2 + 1) * 128 + Q) * 4 + q];
            ah[6] = fdot2(w6.x, hh.x, ah[6]);
            ah[6] = fdot2(w6.y, hh.y, ah[6]);
            ah[6] = fdot2(w6.z, hh.z, ah[6]);
            ah[6] = fdot2(w6.w, hh.w, ah[6]);
            al[6] = fdot2(w6.x, hl.x, al[6]);
            al[6] = fdot2(w6.y, hl.y, al[6]);
            al[6] = fdot2(w6.z, hl.z, al[6]);
            al[6] = fdot2(w6.w, hl.w, al[6]);
            ah[7] = fdot2(w7.x, hh.x, ah[7]);
            ah[7] = fdot2(w7.y, hh.y, ah[7]);
            ah[7] = fdot2(w7.z, hh.z, ah[7]);
            ah[7] = fdot2(w7.w, hh.w, ah[7]);
            al[7] = fdot2(w7.x, hl.x, al[7]);
            al[7] = fdot2(w7.y, hl.y, al[7]);
            al[7] = fdot2(w7.z, hl.z, al[7]);
            al[7] = fdot2(w7.w, hl.w, al[7]);
        }

        // ---- quad reduction (DPP): every lane gets all 8 totals ----
        float tt[8];
        #pragma unroll
        for (int j = 0; j < 8; ++j) tt[j] = quad_reduce(ah[j] + al[j]);

        // static selects on (q&1) — no runtime array indexing (rule #20)
        int odd = q & 1;
        float pi = odd ? tt[1] : tt[0];
        float pf = odd ? tt[3] : tt[2];
        float pg = odd ? tt[5] : tt[4];
        float po = odd ? tt[7] : tt[6];
        float iv = 1.f / (1.f + __expf(-(pi + xi)));
        float fv = 1.f / (1.f + __expf(-(pf + xf)));
        float gv = tanhf(pg + xgg);
        float ov = 1.f / (1.f + __expf(-(po + xo)));
        c = fv * c + iv * gv;
        float nh = ov * tanhf(c);
        hcur = nh;
        __half hh16 = __float2half(nh);
        __half hl16 = __float2half(nh - __half2float(hh16));
        if (q < 2) {
            hckp[rx] = hh16;
            int hidx = (rx >> 6) * 72 + (rx & 63);
            ((__half*)(hbuf + (p ^ 1) * 288))[hidx] = hh16;
            ((__half*)(hbuf + (p ^ 1) * 288 + 144))[hidx] = hl16;
        }
        __syncthreads();
        p ^= 1;
        xgp += G4;
        hckp += H;
    }
    if (q < 2) { h_st[b * H + rx] = hcur; c_st[b * H + rx] = c; }
}

// ---------------- logits via MFMA (unchanged from round 7) ----------------
__global__ __launch_bounds__(64) void k_logits(const __half* __restrict__ hck,
        const __half* __restrict__ woHi, const __half* __restrict__ woLo,
        const float* __restrict__ bo, const int* __restrict__ dlen,
        float* __restrict__ pred, int t0, int Cc) {
    int b = blockIdx.y;
    int ct0 = blockIdx.x * 32;
    if (ct0 >= Cc) return;
    int steps_b = dlen[b];
    int l = threadIdx.x;
    int lhi = l >> 4, llo = l & 15;

    if (t0 + ct0 >= steps_b) {   // whole tile inactive: write -1
        for (int r = 0; r < 32; ++r) {
            int t = t0 + ct0 + r;
            if (r >= Cc - ct0 || t >= STEPS) break;
            float* pr = pred + ((size_t)b * STEPS + t) * VOCAB;
            for (int v = l; v < VOCAB; v += 64) pr[v] = -1.f;
        }
        return;
    }

    uint4 a[2][8];
    #pragma unroll
    for (int m = 0; m < 2; ++m) {
        int rr = ct0 + m * 16 + llo;
        int rc = (rr < Cc) ? rr : (Cc - 1);          // clamp (masked at store)
        const uint4* rp = (const uint4*)(hck + ((size_t)b * Cc + rc) * H);
        #pragma unroll
        for (int kt = 0; kt < 8; ++kt) a[m][kt] = rp[kt * 4 + lhi];
    }

    const uint4* bh4 = (const uint4*)woHi;
    const uint4* bl4 = (const uint4*)woLo;
    for (int vt = 0; vt < VT; ++vt) {
        int v = vt * 16 + llo;
        float bias = (v < VOCAB) ? bo[v] : 0.f;
        f32x4 acc0 = {bias, bias, bias, bias};
        f32x4 acc1 = acc0;
        #pragma unroll
        for (int kt = 0; kt < 8; ++kt) {
            uint4 bh = bh4[(vt * 8 + kt) * 64 + l];
            acc0 = mfma16(a[0][kt], bh, acc0);
            acc1 = mfma16(a[1][kt], bh, acc1);
        }
        #pragma unroll
        for (int kt = 0; kt < 8; ++kt) {
            uint4 bl = bl4[(vt * 8 + kt) * 64 + l];
            acc0 = mfma16(a[0][kt], bl, acc0);
            acc1 = mfma16(a[1][kt], bl, acc1);
        }
        if (v < VOCAB) {
            #pragma unroll
            for (int m = 0; m < 2; ++m) {
                f32x4 A = m ? acc1 : acc0;
                #pragma unroll
                for (int i = 0; i < 4; ++i) {
                    int r = ct0 + m * 16 + lhi * 4 + i;
                    int t = t0 + r;
                    if (r < Cc && t < STEPS)
                        pred[((size_t)b * STEPS + t) * VOCAB + v] =
                            (t < steps_b) ? A[i] : -1.f;
                }
            }
        }
    }
}

extern "C" void kernel_launch(void* const* d_in, const int* in_sizes, int n_in,
                              void* d_out, int out_size, void* d_ws, size_t ws_size,
                              hipStream_t stream) {
    const float* enc   = (const float*)d_in[0];
    const float* caps  = (const float*)d_in[1];
    const float* w_ih  = (const float*)d_in[2];
    const float* w_hh  = (const float*)d_in[3];
    const float* b_ih  = (const float*)d_in[4];
    const float* b_hh  = (const float*)d_in[5];
    const float* W_out = (const float*)d_in[6];
    const float* b_out = (const float*)d_in[7];
    const float* W_emb = (const float*)d_in[8];
    const float* b_emb = (const float*)d_in[9];
    const float* W_h   = (const float*)d_in[10];
    const float* b_h   = (const float*)d_in[11];
    const float* W_c   = (const float*)d_in[12];
    const float* b_c   = (const float*)d_in[13];
    const int*   lens  = (const int*)d_in[14];

    float* out_pred = (float*)d_out;
    float* out_caps = out_pred + (size_t)BS * STEPS * VOCAB;
    float* out_dec  = out_caps + (size_t)BS * T * WV;
    float* out_sidx = out_dec + BS;

    char* w = (char*)d_ws;
    size_t off = 0;
    auto take = [&](size_t bytes) -> char* {
        char* p = w + off;
        off += (bytes + 255) & ~(size_t)255;
        return p;
    };
    int*     sidx = (int*)take(BS * 4);
    int*     dlen = (int*)take(BS * 4);
    float*   Wc   = (float*)take((size_t)G4 * WV * 4);
    float*   bc   = (float*)take(G4 * 4);
    float*   h_st = (float*)take((size_t)BS * H * 4);
    float*   c_st = (float*)take((size_t)BS * H * 4);
    __half2* wR   = (__half2*)take((size_t)G4 * (H / 2) * 4);
    __half*  woHi = (__half*)take((size_t)VT * 8 * 64 * 8 * 2);
    __half*  woLo = (__half*)take((size_t)VT * 8 * 64 * 8 * 2);
    __half*  cHi  = (__half*)take((size_t)BS * T * 128 * 2);
    __half*  cLo  = (__half*)take((size_t)BS * T * 128 * 2);
    __half*  wcHi = (__half*)take((size_t)64 * 4 * 64 * 8 * 2);
    __half*  wcLo = (__half*)take((size_t)64 * 4 * 64 * 8 * 2);

    size_t rem = (ws_size > off) ? (ws_size - off) : 0;
    size_t per_step = (size_t)BS * G4 * 4 + (size_t)BS * H * 2 + 1024;
    int C = (int)(rem / per_step);
    if (C < 1) C = 1;
    if (C > STEPS) C = STEPS;
    float*  xg  = (float*)take((size_t)BS * C * G4 * 4);
    __half* hck = (__half*)take((size_t)BS * C * H * 2);

    // allow 133 KB dynamic LDS for the recurrent kernel (host-side, capture-safe)
    (void)hipFuncSetAttribute((const void*)k_lstm,
                              hipFuncAttributeMaxDynamicSharedMemorySize, LSTM_SMEM);

    k_sort<<<1, 256, 0, stream>>>(lens, sidx, dlen, out_dec, out_sidx);
    k_gather<<<BS, 256, 0, stream>>>(caps, sidx, out_caps);
    k_wcomb<<<G4 * WV / 256, 256, 0, stream>>>(w_ih, W_emb, Wc);
    k_bcomb<<<G4 / 256, 256, 0, stream>>>(w_ih, b_ih, b_hh, b_emb, bc);
    k_packw<<<G4 * (H / 2) / 256, 256, 0, stream>>>(w_hh, wR);
    k_packwo<<<VT * 8 * 64 * 8 / 256, 256, 0, stream>>>(W_out, woHi, woLo);
    k_packcaps<<<BS * T * 128 / 256, 256, 0, stream>>>(out_caps, cHi, cLo);
    k_packwc<<<64 * 4 * 64 * 8 / 256, 256, 0, stream>>>(Wc, wcHi, wcLo);
    k_inithc<<<BS, 256, 0, stream>>>(enc, sidx, W_h, b_h, W_c, b_c, h_st, c_st);

    for (int t0 = 0; t0 < STEPS; t0 += C) {
        int Cc = STEPS - t0; if (Cc > C) Cc = C;
        dim3 gx((Cc + 31) / 32, BS);
        k_xg<<<gx, 256, 0, stream>>>(cHi, cLo, wcHi, wcLo, bc, dlen, xg, t0, Cc);
        k_lstm<<<BS, 512, LSTM_SMEM, stream>>>(wR, xg, dlen, h_st, c_st, hck, t0, Cc);
        k_logits<<<gx, 64, 0, stream>>>(hck, woHi, woLo, b_out, dlen, out_pred, t0, Cc);
    }
}